// Round 9
// baseline (551.892 us; speedup 1.0000x reference)
//
#include <hip/hip_runtime.h>
#include <math.h>

// Problem constants (fixed by setup_inputs)
#define NB 2
#define NL 2048
#define NH 16
#define ND 64
#define NDM 1024
#define NU 409                  // max(1, 2048 // 5)
#define NUP 416                 // NU padded to multiple of 32; 416 = 26*16 = 13*32
#define NBH (NB*NH)             // 32
#define NROWS (NB*NL)           // 4096
#define NRTOT (NB*NH*NL)        // 65536
#define MTOT (NBH*NUP)          // 13312

typedef short bf16x8 __attribute__((ext_vector_type(8)));
typedef short bf16x4 __attribute__((ext_vector_type(4)));
typedef float f32x4  __attribute__((ext_vector_type(4)));

__device__ __forceinline__ short f2bf(float x) {   // RNE f32 -> bf16
  unsigned u = __float_as_uint(x);
  return (short)((u + 0x7FFFu + ((u >> 16) & 1u)) >> 16);
}
__device__ __forceinline__ float bf2f(short s) {
  return __uint_as_float(((unsigned)(unsigned short)s) << 16);
}

__device__ __forceinline__ void gload16(const short* g, short* l) {
  __builtin_amdgcn_global_load_lds(
      (const __attribute__((address_space(1))) void*)g,
      (__attribute__((address_space(3))) void*)l, 16, 0, 0);
}

// ---------------------------------------------------------------- multi-tensor f32 -> bf16 splits
struct SplitDesc { const float* in; short* a; short* b; short* c; int nc; int nblk; };
struct SplitArgs { SplitDesc d[7]; };

__global__ __launch_bounds__(256) void msplit_k(SplitArgs args) {
  const SplitDesc d = args.d[blockIdx.z];
  if ((int)blockIdx.x >= d.nblk) return;
  const size_t i = (size_t)blockIdx.x * 256 + threadIdx.x;
  const float4 x0 = ((const float4*)d.in)[2*i];
  const float4 x1 = ((const float4*)d.in)[2*i + 1];
  float x[8] = {x0.x,x0.y,x0.z,x0.w, x1.x,x1.y,x1.z,x1.w};
  bf16x8 va, vb, vc;
  #pragma unroll
  for (int j = 0; j < 8; ++j) {
    const short A = f2bf(x[j]);
    const float r1 = x[j] - bf2f(A);
    const short B = f2bf(r1);
    va[j] = A; vb[j] = B;
    vc[j] = f2bf(r1 - bf2f(B));
  }
  *(bf16x8*)(d.a + 8*i) = va;
  if (d.nc >= 2) *(bf16x8*)(d.b + 8*i) = vb;
  if (d.nc == 3) *(bf16x8*)(d.c + 8*i) = vc;
}

// ---------------------------------------------------------------- fused split-bf16 MFMA GEMM
// BK=64. Full tile: 128x128, 4 waves 2x2, wave 64x64 (4x4 frags).
// Half tile (K): 64x128, 4 waves 2x2, wave 32x64 (2x4 frags) -> per-block work
// equals a 48-step full tile, so the balanced mega launch has no tail.
// chunk pairs (c=step>>4): c0 (a,a), c1 (a,b), c2 (b,a), c3 (a,c), c4 (c,a), c5 (b,b)
// LDS: linear dest for global_load_lds; SOURCE k-slot pre-swizzled s^=(row&7);
// fragment reads apply the same XOR (rule 21).
// scheme 0 (mega, 1024 blocks): XCD chunks interleave [K,Q,K,V] -> each CU
//   hosts {2K,1Q,1V} with equal total work. scheme 1 (O, 512): split-K halves
//   interleaved per CU.
// mode 0: normal staging, SC-scatter f32 + bias (Q, V)
// mode 1: half tile, fused K epilogue (bias+norm -> Kbf bf16, f64 kbar partials)
// mode 2: X staged from Csel via invsel LDS table, plain f32 out (O)
struct GemmDesc {
  const short* X[3];
  const short* W[3];
  const float* bias;    // may be null
  float* C;             // modes 0/2
  short* Kbf;           // mode 1
  double* kpart;        // mode 1: [bh][64][64] f64
  const int* invsel;    // mode 2
  int sbeg, send;       // step range; one step = 64 k-elems; chunk = step>>4
  int mode;
};
struct GemmArgs { GemmDesc d[3]; };

__global__ __launch_bounds__(256, 4) void gemm_fused_k(GemmArgs args, int scheme) {
  __shared__ short As[128*64];   // 16 KB
  __shared__ short Bs[128*64];   // 16 KB
  __shared__ int utbl[2048];     // 8 KB (mode 2 only)
  const int fid = blockIdx.x;
  const int xcd = fid & 7, jd = fid >> 3;
  int zi, bx, by, half;
  if (scheme == 0) {              // 1024 blocks: [K,Q,K,V] per XCD 4-group
    const int jj = jd >> 2, s = jd & 3;
    if (s == 1)      { const int q = (xcd << 5) + jj; zi = 0; bx = q & 7; by = q >> 3; half = 0; }
    else if (s == 3) { const int v = (xcd << 5) + jj; zi = 2; bx = v & 7; by = v >> 3; half = 0; }
    else             { const int k = (xcd << 6) + (jj << 1) + (s >> 1); zi = 1; bx = k & 7; by = k >> 3; half = 1; }
  } else {                        // 512 blocks: split-K halves interleaved
    zi = jd & 1;
    const int o = (xcd << 5) + (jd >> 1);
    bx = o & 7; by = o >> 3; half = 0;
  }
  const GemmDesc d = args.d[zi];
  const int tid = threadIdx.x;
  const int wv = tid >> 6, L = tid & 63;
  const int lr = L & 15, lg = L >> 4;
  const int n0 = bx << 7;
  const int m0 = by << (half ? 6 : 7);
  const int wm = (wv >> 1) << (half ? 5 : 6);
  const int wn = (wv & 1) << 6;
  const int sr = tid >> 3, ssl = tid & 7;
  const int b2 = by >> 4;                         // batch for full-tile modes

  if (d.mode == 2) {
    #pragma unroll
    for (int e = 0; e < 8; ++e) {
      const int idx = (tid << 3) + e;             // 0..2047
      const int row = idx >> 4, h = idx & 15;
      utbl[idx] = d.invsel[((((size_t)b2 << 4) + h) << 11) + ((m0 + row) & (NL - 1))];
    }
    __syncthreads();
  }

  f32x4 acc[4][4];
  #pragma unroll
  for (int i = 0; i < 4; ++i)
    #pragma unroll
    for (int j = 0; j < 4; ++j) acc[i][j] = (f32x4){0.f,0.f,0.f,0.f};

  for (int step = d.sbeg; step < d.send; ++step) {
    const int c = step >> 4, kk = (step & 15) << 6;
    const short *Xg, *Wg;
    switch (c) {
      case 0:  Xg = d.X[0]; Wg = d.W[0]; break;
      case 1:  Xg = d.X[0]; Wg = d.W[1]; break;
      case 2:  Xg = d.X[1]; Wg = d.W[0]; break;
      case 3:  Xg = d.X[0]; Wg = d.W[2]; break;
      case 4:  Xg = d.X[2]; Wg = d.W[0]; break;
      default: Xg = d.X[1]; Wg = d.W[1]; break;
    }
    if (half) {
      #pragma unroll
      for (int j = 0; j < 2; ++j) {
        const int row = (j << 5) + sr;
        const int slot = (ssl ^ (row & 7)) << 3;
        gload16(Xg + (size_t)(m0 + row) * NDM + kk + slot, As + (j << 11) + (tid << 3));
      }
      #pragma unroll
      for (int j = 0; j < 4; ++j) {
        const int row = (j << 5) + sr;
        const int slot = (ssl ^ (row & 7)) << 3;
        gload16(Wg + (size_t)(n0 + row) * NDM + kk + slot, Bs + (j << 11) + (tid << 3));
      }
    } else {
      #pragma unroll
      for (int j = 0; j < 4; ++j) {
        const int row = (j << 5) + sr;
        const int slot = (ssl ^ (row & 7)) << 3;
        const short* xsrc;
        if (d.mode == 2) {
          const int h = step & 15;                // one head per 64-wide step
          const int u = utbl[(row << 4) + h];
          xsrc = Xg + (((size_t)((b2 << 4) + h) * NUP + u) << 6) + slot;
        } else {
          xsrc = Xg + (size_t)(m0 + row) * NDM + kk + slot;
        }
        gload16(xsrc, As + (j << 11) + (tid << 3));
        gload16(Wg + (size_t)(n0 + row) * NDM + kk + slot, Bs + (j << 11) + (tid << 3));
      }
    }
    __syncthreads();
    if (half) {
      #pragma unroll
      for (int c2 = 0; c2 < 2; ++c2) {
        const int sl = (((c2 << 2) + lg) ^ (lr & 7)) << 3;
        bf16x8 af[2], bfr[4];
        #pragma unroll
        for (int t = 0; t < 2; ++t)
          af[t] = *(const bf16x8*)(As + ((wm + (t << 4) + lr) << 6) + sl);
        #pragma unroll
        for (int t = 0; t < 4; ++t)
          bfr[t] = *(const bf16x8*)(Bs + ((wn + (t << 4) + lr) << 6) + sl);
        #pragma unroll
        for (int mt = 0; mt < 2; ++mt)
          #pragma unroll
          for (int nt = 0; nt < 4; ++nt)
            acc[mt][nt] = __builtin_amdgcn_mfma_f32_16x16x32_bf16(bfr[nt], af[mt], acc[mt][nt], 0, 0, 0);
      }
    } else {
      #pragma unroll
      for (int c2 = 0; c2 < 2; ++c2) {
        const int sl = (((c2 << 2) + lg) ^ (lr & 7)) << 3;
        bf16x8 af[4], bfr[4];
        #pragma unroll
        for (int t = 0; t < 4; ++t) {
          af[t]  = *(const bf16x8*)(As + ((wm + (t << 4) + lr) << 6) + sl);
          bfr[t] = *(const bf16x8*)(Bs + ((wn + (t << 4) + lr) << 6) + sl);
        }
        #pragma unroll
        for (int mt = 0; mt < 4; ++mt)
          #pragma unroll
          for (int nt = 0; nt < 4; ++nt)
            acc[mt][nt] = __builtin_amdgcn_mfma_f32_16x16x32_bf16(bfr[nt], af[mt], acc[mt][nt], 0, 0, 0);
      }
    }
    __syncthreads();
  }

  if (d.mode == 1) {
    // ---- fused K epilogue (half tile): k = acc + bias; |k| via shfl over lg;
    //      Kbf bf16 store; f64 kbar partials reduced over lr lanes.
    const int hw = (bx << 1) + (wv & 1);          // head of this wave
    const int bh = ((by >> 5) << 4) + hw;
    const int seg = ((by & 31) << 1) + (wv >> 1); // 32-row segment, 64 per bh
    float kv[2][4][4];
    double inv[2];
    #pragma unroll
    for (int mt = 0; mt < 2; ++mt) {
      float ss = 0.f;
      #pragma unroll
      for (int nt = 0; nt < 4; ++nt) {
        const int n = n0 + wn + (nt << 4) + (lg << 2);
        const float4 b4 = *(const float4*)(d.bias + n);
        kv[mt][nt][0] = acc[mt][nt][0] + b4.x;
        kv[mt][nt][1] = acc[mt][nt][1] + b4.y;
        kv[mt][nt][2] = acc[mt][nt][2] + b4.z;
        kv[mt][nt][3] = acc[mt][nt][3] + b4.w;
        #pragma unroll
        for (int j = 0; j < 4; ++j) ss += kv[mt][nt][j] * kv[mt][nt][j];
      }
      ss += __shfl_xor(ss, 16);
      ss += __shfl_xor(ss, 32);
      inv[mt] = 1.0 / sqrt((double)ss);
    }
    #pragma unroll
    for (int mt = 0; mt < 2; ++mt) {
      const int l = (m0 + wm + (mt << 4) + lr) & (NL - 1);
      short* kp = d.Kbf + (((size_t)bh * NL + l) << 6);
      #pragma unroll
      for (int nt = 0; nt < 4; ++nt) {
        const int dd = (nt << 4) + (lg << 2);
        bf16x4 o;
        #pragma unroll
        for (int j = 0; j < 4; ++j) o[j] = f2bf(kv[mt][nt][j]);
        *(bf16x4*)(kp + dd) = o;
      }
    }
    #pragma unroll
    for (int nt = 0; nt < 4; ++nt) {
      double p[4];
      #pragma unroll
      for (int j = 0; j < 4; ++j) {
        p[j] = (double)kv[0][nt][j] * inv[0] + (double)kv[1][nt][j] * inv[1];
        p[j] += __shfl_xor(p[j], 1);
        p[j] += __shfl_xor(p[j], 2);
        p[j] += __shfl_xor(p[j], 4);
        p[j] += __shfl_xor(p[j], 8);
      }
      if (lr == 0) {
        const int dd = (nt << 4) + (lg << 2);
        double* kp = d.kpart + ((((size_t)bh << 6) + seg) << 6) + dd;
        kp[0] = p[0]; kp[1] = p[1]; kp[2] = p[2]; kp[3] = p[3];
      }
    }
  } else {
    #pragma unroll
    for (int nt = 0; nt < 4; ++nt) {
      const int n = n0 + wn + (nt << 4) + (lg << 2);
      float4 b4 = make_float4(0.f, 0.f, 0.f, 0.f);
      if (d.bias) b4 = *(const float4*)(d.bias + n);
      #pragma unroll
      for (int mt = 0; mt < 4; ++mt) {
        f32x4 a = acc[mt][nt];
        a[0] += b4.x; a[1] += b4.y; a[2] += b4.z; a[3] += b4.w;
        const int m = m0 + wm + (mt << 4) + lr;
        if (d.mode == 0) {   // scatter into (B,H,L,D)
          const int bb = m >> 11, ll = m & (NL - 1);
          const int hh = n >> 6, dd = n & 63;
          *(f32x4*)(d.C + (((size_t)(bb*NH + hh)*NL + ll) << 6) + dd) = a;
        } else {
          *(f32x4*)(d.C + ((size_t)m << 10) + n) = a;
        }
      }
    }
  }
}

// ---------------------------------------------------------------- wtilde (+inline kbar reduce): wt[bh][j] f32, s0[bh] f64
__global__ __launch_bounds__(256) void wtilde_k(const float* __restrict__ Wq,
                                                const float* __restrict__ bq,
                                                const double* __restrict__ kpart,
                                                float* __restrict__ wt,
                                                double* __restrict__ s0) {
  __shared__ double kb[64];
  const int bh = blockIdx.x, h = bh & 15;
  const int tid = threadIdx.x;
  if (tid < 64) {
    double s = 0.0;
    #pragma unroll
    for (int seg = 0; seg < 64; ++seg)
      s += kpart[((((size_t)bh << 6) + seg) << 6) + tid];
    kb[tid] = s * (1.0 / NL);
  }
  __syncthreads();
  const int j = (blockIdx.y << 8) + tid;
  double a = 0.0;
  #pragma unroll 8
  for (int d = 0; d < 64; ++d)
    a += (double)Wq[(((size_t)((h << 6) + d)) << 10) + j] * kb[d];
  wt[((size_t)bh << 10) + j] = (float)a;
  if (blockIdx.y == 0 && tid < 64) {
    double p = (double)bq[(h << 6) + tid] * kb[tid];
    #pragma unroll
    for (int off = 32; off > 0; off >>= 1) p += __shfl_xor(p, off);
    if (tid == 0) s0[bh] = p;
  }
}

// ---------------------------------------------------------------- fused dotq+msq: ms[bh][l] = (x.wt + s0)/|q|
__global__ __launch_bounds__(256) void dotqms_k(const float* __restrict__ x,
                                                const float* __restrict__ Qb,
                                                const float* __restrict__ wt,
                                                const double* __restrict__ s0,
                                                float* __restrict__ ms) {
  __shared__ float xs[1024];
  __shared__ double sm[16][16];
  __shared__ double sq[16][16];
  const int r = blockIdx.x, b = r >> 11, l = r & (NL - 1);
  const int tid = threadIdx.x;
  ((float4*)xs)[tid] = ((const float4*)(x + ((size_t)r << 10)))[tid];
  __syncthreads();
  const int h = tid >> 4, t = tid & 15;
  const float* w = wt + ((size_t)((b << 4) + h) << 10);
  double a = 0.0;
  #pragma unroll 8
  for (int i = 0; i < 64; ++i) {
    const int j = t + (i << 4);
    a += (double)xs[j] * (double)w[j];
  }
  sm[h][t] = a;
  const float4 qv = *(const float4*)(Qb + (((size_t)((b << 4) + h) * NL + l) << 6) + (t << 2));
  sq[h][t] = (double)qv.x*qv.x + (double)qv.y*qv.y + (double)qv.z*qv.z + (double)qv.w*qv.w;
  __syncthreads();
  if (tid < 16) {
    double s = 0.0, ssq = 0.0;
    #pragma unroll
    for (int t2 = 0; t2 < 16; ++t2) { s += sm[tid][t2]; ssq += sq[tid][t2]; }
    ms[(((size_t)(b << 4) + tid) << 11) + l] = (float)((s + s0[(b << 4) + tid]) / sqrt(ssq));
  }
}

// ---------------------------------------------------------------- rank-based top-NU selection (+ inverse map; pad -> NU)
__global__ __launch_bounds__(256) void select_rank_k(const float* __restrict__ ms,
                                                     int* __restrict__ sel,
                                                     int* __restrict__ invsel) {
  __shared__ unsigned long long keys[NL];
  const int bh = blockIdx.x >> 3, seg = blockIdx.x & 7;
  const int tid = threadIdx.x;
  for (int l = tid; l < NL; l += 256) {
    unsigned u = __float_as_uint(ms[(size_t)bh * NL + l]);
    u = (u & 0x80000000u) ? ~u : (u | 0x80000000u);   // order-preserving map
    keys[l] = ((unsigned long long)u << 32) | (unsigned)(NL - 1 - l);
  }
  __syncthreads();
  const int r = (seg << 8) + tid;
  const unsigned long long mine = keys[r];
  int cnt = 0;
  #pragma unroll 8
  for (int l = 0; l < NL; ++l) cnt += (keys[l] > mine) ? 1 : 0;
  if (cnt < NU) sel[bh*NU + cnt] = r;
  invsel[(size_t)bh * NL + r] = (cnt < NU) ? cnt : NU;  // NU = zeroed pad row
}

// ---------------------------------------------------------------- V (bh,l,d) f32 -> Vt (bh,d,l) bf16
__global__ __launch_bounds__(256) void transpose_v_k(const float* __restrict__ V0,
                                                     short* __restrict__ Vt) {
  __shared__ float Ts[64][65];
  const int bh = blockIdx.x >> 5, lt = blockIdx.x & 31;
  const int l0 = lt << 6, tid = threadIdx.x;
  const int lr = tid >> 2, j = tid & 3;
  const size_t rowo = ((size_t)bh*NL + l0 + lr) << 6;
  #pragma unroll
  for (int s = 0; s < 4; ++s) {
    const int dd = (j + 4*s) << 2;
    const float4 v = *(const float4*)(V0 + rowo + dd);
    Ts[lr][dd+0] = v.x; Ts[lr][dd+1] = v.y; Ts[lr][dd+2] = v.z; Ts[lr][dd+3] = v.w;
  }
  __syncthreads();
  const int d = tid >> 2, lc = (tid & 3) << 4;
  short* dst = Vt + ((size_t)bh*ND + d) * NL + l0 + lc;
  bf16x8 o0, o1;
  #pragma unroll
  for (int i = 0; i < 8; ++i) {
    o0[i] = f2bf(Ts[lc + i][d]);
    o1[i] = f2bf(Ts[lc + 8 + i][d]);
  }
  *(bf16x8*)dst = o0;
  *(bf16x8*)(dst + 8) = o1;
}

// ---------------------------------------------------------------- fused attention with inline Q gather; split bf16 Csel out
__global__ __launch_bounds__(512) void fattn_k(const float* __restrict__ Qb,
                                               const int* __restrict__ sel,
                                               const short* __restrict__ Kbf,
                                               const short* __restrict__ Vt,
                                               short* __restrict__ Ca,
                                               short* __restrict__ Cb) {
  __shared__ short S[32*2048];        // 128 KB, row stride 4096 B
  __shared__ float inv_s[32];
  int bid = blockIdx.x;
  bid = (bid & 7) * 52 + (bid >> 3);  // 416 = 8*52 XCD chunks
  const int m0 = bid << 5;
  const int bh = m0 / NUP;
  const int u0 = m0 - bh * NUP;
  const int tid = threadIdx.x;
  const int w = tid >> 6, L = tid & 63;
  const int lr = L & 15, lg = L >> 4;

  // ---- Q fragments gathered from f32 Qb via sel (pad rows read row 0, discarded)
  bf16x8 qf[2][2];
  #pragma unroll
  for (int mt = 0; mt < 2; ++mt) {
    const int u = u0 + mt*16 + lr;
    const int lq = (u < NU) ? sel[bh*NU + u] : 0;
    const float* qp = Qb + (((size_t)bh*NL + lq) << 6) + lg*8;
    const float4 q0 = *(const float4*)qp;
    const float4 q1 = *(const float4*)(qp + 4);
    const float4 q2 = *(const float4*)(qp + 32);
    const float4 q3 = *(const float4*)(qp + 36);
    qf[mt][0][0]=f2bf(q0.x); qf[mt][0][1]=f2bf(q0.y); qf[mt][0][2]=f2bf(q0.z); qf[mt][0][3]=f2bf(q0.w);
    qf[mt][0][4]=f2bf(q1.x); qf[mt][0][5]=f2bf(q1.y); qf[mt][0][6]=f2bf(q1.z); qf[mt][0][7]=f2bf(q1.w);
    qf[mt][1][0]=f2bf(q2.x); qf[mt][1][1]=f2bf(q2.y); qf[mt][1][2]=f2bf(q2.z); qf[mt][1][3]=f2bf(q2.w);
    qf[mt][1][4]=f2bf(q3.x); qf[mt][1][5]=f2bf(q3.y); qf[mt][1][6]=f2bf(q3.z); qf[mt][1][7]=f2bf(q3.w);
  }
  const int nb = w << 8;
  const short* kb0 = Kbf + (((size_t)bh*NL + nb + lr) << 6) + lg*8;
  #pragma unroll 2
  for (int nt = 0; nt < 16; ++nt) {
    const short* kp = kb0 + ((size_t)nt << 10);
    const bf16x8 kf0 = *(const bf16x8*)kp;
    const bf16x8 kf1 = *(const bf16x8*)(kp + 32);
    #pragma unroll
    for (int mt = 0; mt < 2; ++mt) {
      f32x4 a = {0.f,0.f,0.f,0.f};
      a = __builtin_amdgcn_mfma_f32_16x16x32_bf16(kf0, qf[mt][0], a, 0, 0, 0);
      a = __builtin_amdgcn_mfma_f32_16x16x32_bf16(kf1, qf[mt][1], a, 0, 0, 0);
      const int m = mt*16 + lr;
      bf16x4 o;
      #pragma unroll
      for (int r = 0; r < 4; ++r) o[r] = f2bf(a[r] * 0.125f);
      const int byteoff = (m << 12) + ((((nb + nt*16 + lg*4) << 1)) ^ ((m & 7) << 4));
      *(bf16x4*)((char*)S + byteoff) = o;
    }
  }
  __syncthreads();

  #pragma unroll
  for (int j = 0; j < 4; ++j) {
    const int R = (w << 2) + j;
    char* rowp = (char*)S + (R << 12);
    const int sw = (R & 7) << 4;
    bf16x8 v[4];
    #pragma unroll
    for (int i = 0; i < 4; ++i)
      v[i] = *(const bf16x8*)(rowp + (((L << 6) + (i << 4)) ^ sw));
    float f[32];
    #pragma unroll
    for (int i = 0; i < 4; ++i)
      #pragma unroll
      for (int e = 0; e < 8; ++e) f[i*8+e] = bf2f(v[i][e]);
    float mx = f[0];
    #pragma unroll
    for (int i = 1; i < 32; ++i) mx = fmaxf(mx, f[i]);
    #pragma unroll
    for (int off = 32; off > 0; off >>= 1) mx = fmaxf(mx, __shfl_xor(mx, off));
    float sum = 0.f;
    #pragma unroll
    for (int i = 0; i < 32; ++i) { f[i] = __expf(f[i] - mx); sum += f[i]; }
    #pragma unroll
    for (int off = 32; off > 0; off >>= 1) sum += __shfl_xor(sum, off);
    bf16x8 p[4];
    #pragma unroll
    for (int i = 0; i < 4; ++i)
      #pragma unroll
      for (int e = 0; e < 8; ++e) p[i][e] = f2bf(f[i*8+e]);
    #pragma unroll
    for (int i = 0; i < 4; ++i)
      *(bf16x8*)(rowp + (((L << 6) + (i << 4)) ^ sw)) = p[i];
    if (L == 0) inv_s[R] = 1.f / sum;
  }
  __syncthreads();

  {
    const int mt = w & 1, dt = w >> 1;
    const int m = mt*16 + lr;
    const char* arow = (const char*)S + (m << 12);
    const int sw = (m & 7) << 4;
    const short* vrow = Vt + (((size_t)bh*ND + dt*16 + lr) << 11) + lg*8;
    f32x4 acc0 = {0.f,0.f,0.f,0.f}, acc1 = {0.f,0.f,0.f,0.f};
    for (int k0 = 0; k0 < NL; k0 += 64) {
      const bf16x8 p0 = *(const bf16x8*)(arow + ((((k0 + lg*8) << 1)) ^ sw));
      const bf16x8 p1 = *(const bf16x8*)(arow + ((((k0 + 32 + lg*8) << 1)) ^ sw));
      const bf16x8 v0 = *(const bf16x8*)(vrow + k0);
      const bf16x8 v1 = *(const bf16x8*)(vrow + k0 + 32);
      acc0 = __builtin_amdgcn_mfma_f32_16x16x32_bf16(p0, v0, acc0, 0, 0, 0);
      acc1 = __builtin_amdgcn_mfma_f32_16x16x32_bf16(p1, v1, acc1, 0, 0, 0);
    }
    const int ub = u0 + mt*16 + (lg << 2);
    #pragma unroll
    for (int r = 0; r < 4; ++r) {
      float val = (acc0[r] + acc1[r]) * inv_s[mt*16 + (lg << 2) + r];
      if (ub + r >= NU) val = 0.f;                 // zero pad rows (incl. row NU)
      const size_t off = (((size_t)m0 + mt*16 + (lg << 2) + r) << 6) + dt*16 + lr;
      const short A = f2bf(val);
      Ca[off] = A;
      Cb[off] = f2bf(val - bf2f(A));
    }
  }
}

// ---------------------------------------------------------------- out += P1 + bias
__global__ __launch_bounds__(256) void oadd_k(float* __restrict__ out,
                                              const float* __restrict__ P1,
                                              const float* __restrict__ bo) {
  const size_t i4 = (size_t)blockIdx.x * 256 + threadIdx.x;
  const size_t i = i4 << 2;
  float4 a = *(float4*)(out + i);
  const float4 b = *(const float4*)(P1 + i);
  const float4 c = *(const float4*)(bo + ((i4 & 255) << 2));
  a.x += b.x + c.x; a.y += b.y + c.y; a.z += b.z + c.z; a.w += b.w + c.w;
  *(float4*)(out + i) = a;
}

// ---------------------------------------------------------------- launch
extern "C" void kernel_launch(void* const* d_in, const int* in_sizes, int n_in,
                              void* d_out, int out_size, void* d_ws, size_t ws_size,
                              hipStream_t stream)
{
  (void)in_sizes; (void)n_in; (void)out_size; (void)ws_size;
  const float* queries = (const float*)d_in[0];
  const float* keys    = (const float*)d_in[1];
  const float* values  = (const float*)d_in[2];
  const float* Wq = (const float*)d_in[3];  const float* bq = (const float*)d_in[4];
  const float* Wk = (const float*)d_in[5];  const float* bk = (const float*)d_in[6];
  const float* Wv = (const float*)d_in[7];  const float* bv = (const float*)d_in[8];
  const float* Wo = (const float*)d_in[9];  const float* bo = (const float*)d_in[10];
  float* out = (float*)d_out;

  char* base = (char*)d_ws;
  #define MB(x) ((size_t)(x) << 20)

  short* Qa   = (short*)(base + MB(0));    // 8 MiB  -> Vt after mega
  short* Qb2  = (short*)(base + MB(8));    // 8 MiB  -> CselA/CselB after mega
  short* Ka   = (short*)(base + MB(16));
  short* Kb2  = (short*)(base + MB(24));
  short* Kc   = (short*)(base + MB(32));
  short* Vbf  = (short*)(base + MB(40));
  float* Qb   = (float*)(base + MB(48));   // 16 MiB -> P1o after fattn
  short* Kbf  = (short*)(base + MB(64));   // 8 MiB
  short* Wqa  = (short*)(base + MB(72));
  short* Wqb  = (short*)(base + MB(74));
  short* Wka  = (short*)(base + MB(76));
  short* Wkb  = (short*)(base + MB(78));
  short* Wkc  = (short*)(base + MB(80));
  short* Wvbf = (short*)(base + MB(82));
  short* Woa  = (short*)(base + MB(84));
  short* Wob  = (short*)(base + MB(86));
  char* sm = base + MB(88);
  double* kpart  = (double*)sm;  sm += 1048576;   // [32][64][64] f64
  float*  wt     = (float*)sm;   sm += 131072;    // [32][1024] f32
  double* s0     = (double*)sm;  sm += 512;
  float*  msb    = (float*)sm;   sm += 262144;
  int*    sel    = (int*)sm;     sm += 65536;
  int*    invsel = (int*)sm;     sm += 262144;

  // time-multiplexed aliases
  float* Vp    = out;                       // V projection scratch (fully overwritten later)
  short* Vt    = Qa;                        // after mega
  short* CselA = Qb2;                       // 1.625 MiB
  short* CselB = (short*)(base + MB(10));   // 1.625 MiB
  float* P1o   = Qb;                        // after fattn

  // ---- 1: all splits in one launch (inputs + weights)
  {
    SplitArgs a;
    a.d[0] = {queries, Qa, Qb2, nullptr, 2, 2048};
    a.d[1] = {keys,    Ka, Kb2, Kc,      3, 2048};
    a.d[2] = {values,  Vbf, nullptr, nullptr, 1, 2048};
    a.d[3] = {Wq, Wqa, Wqb, nullptr, 2, 512};
    a.d[4] = {Wk, Wka, Wkb, Wkc,     3, 512};
    a.d[5] = {Wv, Wvbf, nullptr, nullptr, 1, 512};
    a.d[6] = {Wo, Woa, Wob, nullptr, 2, 512};
    msplit_k<<<dim3(2048,1,7), 256, 0, stream>>>(a);
  }
  // ---- 2: balanced mega GEMM: Q(3-prod, full tile) + K(6-prod, half tile,
  //         fused epilogue) + V(1-prod, full tile); 1024 blocks, 4/CU, no tail
  {
    GemmArgs g;
    g.d[0] = {{Qa,Qb2,Qa}, {Wqa,Wqb,Wqa}, bq, Qb, nullptr, nullptr, nullptr, 0, 48, 0};
    g.d[1] = {{Ka,Kb2,Kc}, {Wka,Wkb,Wkc}, bk, nullptr, Kbf, kpart, nullptr, 0, 96, 1};
    g.d[2] = {{Vbf,Vbf,Vbf}, {Wvbf,Wvbf,Wvbf}, bv, Vp, nullptr, nullptr, nullptr, 0, 16, 0};
    gemm_fused_k<<<1024, 256, 0, stream>>>(g, 0);
  }
  // ---- 3-6: V transpose + ranking chain
  transpose_v_k<<<NBH*32, 256, 0, stream>>>(Vp, Vt);
  wtilde_k<<<dim3(NBH,4), 256, 0, stream>>>(Wq, bq, kpart, wt, s0);
  dotqms_k<<<NROWS, 256, 0, stream>>>(queries, Qb, wt, s0, msb);
  select_rank_k<<<NBH*8, 256, 0, stream>>>(msb, sel, invsel);

  // ---- 7: fused attention (inline Q gather; split bf16 Csel; pad rows zeroed)
  fattn_k<<<MTOT/32, 512, 0, stream>>>(Qb, sel, Kbf, Vt, CselA, CselB);

  // ---- 8: output projection (X gathered from Csel via invsel), split-K 2-way
  {
    GemmArgs g;
    g.d[0] = {{CselA,CselB,CselA}, {Woa,Wob,Woa}, nullptr, out, nullptr, nullptr, invsel, 0, 24, 2};
    g.d[1] = {{CselA,CselB,CselA}, {Woa,Wob,Woa}, nullptr, P1o, nullptr, nullptr, invsel, 24, 48, 2};
    g.d[2] = g.d[0];
    gemm_fused_k<<<512, 256, 0, stream>>>(g, 1);
  }
  // ---- 9: combine + bias
  oadd_k<<<4096, 256, 0, stream>>>(out, P1o, bo);
}

// Round 10
// 358.555 us; speedup vs baseline: 1.5392x; 1.5392x over previous
//
#include <hip/hip_runtime.h>
#include <math.h>

// Problem constants (fixed by setup_inputs)
#define NB 2
#define NL 2048
#define NH 16
#define ND 64
#define NDM 1024
#define NU 409                  // max(1, 2048 // 5)
#define NUP 416                 // NU padded to multiple of 32; 416 = 26*16 = 13*32
#define NBH (NB*NH)             // 32
#define NROWS (NB*NL)           // 4096
#define NRTOT (NB*NH*NL)        // 65536
#define MTOT (NBH*NUP)          // 13312

typedef short bf16x8 __attribute__((ext_vector_type(8)));
typedef short bf16x4 __attribute__((ext_vector_type(4)));
typedef float f32x4  __attribute__((ext_vector_type(4)));

__device__ __forceinline__ short f2bf(float x) {   // RNE f32 -> bf16
  unsigned u = __float_as_uint(x);
  return (short)((u + 0x7FFFu + ((u >> 16) & 1u)) >> 16);
}
__device__ __forceinline__ float bf2f(short s) {
  return __uint_as_float(((unsigned)(unsigned short)s) << 16);
}

__device__ __forceinline__ void gload16(const short* g, short* l) {
  __builtin_amdgcn_global_load_lds(
      (const __attribute__((address_space(1))) void*)g,
      (__attribute__((address_space(3))) void*)l, 16, 0, 0);
}

// ---------------------------------------------------------------- multi-tensor f32 -> bf16 splits
struct SplitDesc { const float* in; short* a; short* b; short* c; int nc; int nblk; };
struct SplitArgs { SplitDesc d[7]; };

__global__ __launch_bounds__(256) void msplit_k(SplitArgs args) {
  const SplitDesc d = args.d[blockIdx.z];
  if ((int)blockIdx.x >= d.nblk) return;
  const size_t i = (size_t)blockIdx.x * 256 + threadIdx.x;
  const float4 x0 = ((const float4*)d.in)[2*i];
  const float4 x1 = ((const float4*)d.in)[2*i + 1];
  float x[8] = {x0.x,x0.y,x0.z,x0.w, x1.x,x1.y,x1.z,x1.w};
  bf16x8 va, vb, vc;
  #pragma unroll
  for (int j = 0; j < 8; ++j) {
    const short A = f2bf(x[j]);
    const float r1 = x[j] - bf2f(A);
    const short B = f2bf(r1);
    va[j] = A; vb[j] = B;
    vc[j] = f2bf(r1 - bf2f(B));
  }
  *(bf16x8*)(d.a + 8*i) = va;
  if (d.nc >= 2) *(bf16x8*)(d.b + 8*i) = vb;
  if (d.nc == 3) *(bf16x8*)(d.c + 8*i) = vc;
}

// ---------------------------------------------------------------- mega projection GEMM (Q/K/V)
// BK=64. Full tile: 128x128, 4 waves 2x2, wave 64x64 (4x4 frags).
// Half tile (K): 64x128, wave 32x64 (2x4 frags) -> per-block work equals a
// 48-step full tile, so the 1024-block launch is balanced (no tail).
// chunk pairs (c=step>>4): c0 (a,a), c1 (a,b), c2 (b,a), c3 (a,c), c4 (c,a), c5 (b,b)
// LDS: linear dest for global_load_lds; SOURCE k-slot pre-swizzled s^=(row&7);
// fragment reads apply the same XOR (rule 21).
// Decode: 1024 blocks; XCD chunks interleave [K,Q,K,V] -> each CU hosts
// {2K,1Q,1V} with equal total work.
// mode 0: SC-scatter f32 + bias (Q, V)
// mode 1: half tile, fused K epilogue (bias+norm -> Kbf bf16, f64 kbar partials)
struct GemmDesc {
  const short* X[3];
  const short* W[3];
  const float* bias;
  float* C;             // mode 0
  short* Kbf;           // mode 1
  double* kpart;        // mode 1: [bh][64][64] f64
  int sbeg, send;       // step range; one step = 64 k-elems; chunk = step>>4
  int mode;
};
struct GemmArgs { GemmDesc d[3]; };

__global__ __launch_bounds__(256, 3) void gemm_mega_k(GemmArgs args) {
  __shared__ short As[128*64];   // 16 KB
  __shared__ short Bs[128*64];   // 16 KB
  const int fid = blockIdx.x;
  const int xcd = fid & 7, jd = fid >> 3;
  int zi, bx, by, half;
  {                               // [K,Q,K,V] per XCD 4-group
    const int jj = jd >> 2, s = jd & 3;
    if (s == 1)      { const int q = (xcd << 5) + jj; zi = 0; bx = q & 7; by = q >> 3; half = 0; }
    else if (s == 3) { const int v = (xcd << 5) + jj; zi = 2; bx = v & 7; by = v >> 3; half = 0; }
    else             { const int k = (xcd << 6) + (jj << 1) + (s >> 1); zi = 1; bx = k & 7; by = k >> 3; half = 1; }
  }
  const GemmDesc d = args.d[zi];
  const int tid = threadIdx.x;
  const int wv = tid >> 6, L = tid & 63;
  const int lr = L & 15, lg = L >> 4;
  const int n0 = bx << 7;
  const int m0 = by << (half ? 6 : 7);
  const int wm = (wv >> 1) << (half ? 5 : 6);
  const int wn = (wv & 1) << 6;
  const int sr = tid >> 3, ssl = tid & 7;
  const int b2 = by >> 4;                         // batch for full-tile modes

  f32x4 acc[4][4];
  #pragma unroll
  for (int i = 0; i < 4; ++i)
    #pragma unroll
    for (int j = 0; j < 4; ++j) acc[i][j] = (f32x4){0.f,0.f,0.f,0.f};

  for (int step = d.sbeg; step < d.send; ++step) {
    const int c = step >> 4, kk = (step & 15) << 6;
    const short *Xg, *Wg;
    switch (c) {
      case 0:  Xg = d.X[0]; Wg = d.W[0]; break;
      case 1:  Xg = d.X[0]; Wg = d.W[1]; break;
      case 2:  Xg = d.X[1]; Wg = d.W[0]; break;
      case 3:  Xg = d.X[0]; Wg = d.W[2]; break;
      case 4:  Xg = d.X[2]; Wg = d.W[0]; break;
      default: Xg = d.X[1]; Wg = d.W[1]; break;
    }
    if (half) {
      #pragma unroll
      for (int j = 0; j < 2; ++j) {
        const int row = (j << 5) + sr;
        const int slot = (ssl ^ (row & 7)) << 3;
        gload16(Xg + (size_t)(m0 + row) * NDM + kk + slot, As + (j << 11) + (tid << 3));
      }
      #pragma unroll
      for (int j = 0; j < 4; ++j) {
        const int row = (j << 5) + sr;
        const int slot = (ssl ^ (row & 7)) << 3;
        gload16(Wg + (size_t)(n0 + row) * NDM + kk + slot, Bs + (j << 11) + (tid << 3));
      }
    } else {
      #pragma unroll
      for (int j = 0; j < 4; ++j) {
        const int row = (j << 5) + sr;
        const int slot = (ssl ^ (row & 7)) << 3;
        gload16(Xg + (size_t)(m0 + row) * NDM + kk + slot, As + (j << 11) + (tid << 3));
        gload16(Wg + (size_t)(n0 + row) * NDM + kk + slot, Bs + (j << 11) + (tid << 3));
      }
    }
    __syncthreads();
    if (half) {
      #pragma unroll
      for (int c2 = 0; c2 < 2; ++c2) {
        const int sl = (((c2 << 2) + lg) ^ (lr & 7)) << 3;
        bf16x8 af[2], bfr[4];
        #pragma unroll
        for (int t = 0; t < 2; ++t)
          af[t] = *(const bf16x8*)(As + ((wm + (t << 4) + lr) << 6) + sl);
        #pragma unroll
        for (int t = 0; t < 4; ++t)
          bfr[t] = *(const bf16x8*)(Bs + ((wn + (t << 4) + lr) << 6) + sl);
        #pragma unroll
        for (int mt = 0; mt < 2; ++mt)
          #pragma unroll
          for (int nt = 0; nt < 4; ++nt)
            acc[mt][nt] = __builtin_amdgcn_mfma_f32_16x16x32_bf16(bfr[nt], af[mt], acc[mt][nt], 0, 0, 0);
      }
    } else {
      #pragma unroll
      for (int c2 = 0; c2 < 2; ++c2) {
        const int sl = (((c2 << 2) + lg) ^ (lr & 7)) << 3;
        bf16x8 af[4], bfr[4];
        #pragma unroll
        for (int t = 0; t < 4; ++t) {
          af[t]  = *(const bf16x8*)(As + ((wm + (t << 4) + lr) << 6) + sl);
          bfr[t] = *(const bf16x8*)(Bs + ((wn + (t << 4) + lr) << 6) + sl);
        }
        #pragma unroll
        for (int mt = 0; mt < 4; ++mt)
          #pragma unroll
          for (int nt = 0; nt < 4; ++nt)
            acc[mt][nt] = __builtin_amdgcn_mfma_f32_16x16x32_bf16(bfr[nt], af[mt], acc[mt][nt], 0, 0, 0);
      }
    }
    __syncthreads();
  }

  if (d.mode == 1) {
    // ---- fused K epilogue (half tile): k = acc + bias; |k| via shfl over lg;
    //      Kbf bf16 store; f64 kbar partials reduced over lr lanes.
    const int hw = (bx << 1) + (wv & 1);          // head of this wave
    const int bh = ((by >> 5) << 4) + hw;
    const int seg = ((by & 31) << 1) + (wv >> 1); // 32-row segment, 64 per bh
    float kv[2][4][4];
    double inv[2];
    #pragma unroll
    for (int mt = 0; mt < 2; ++mt) {
      float ss = 0.f;
      #pragma unroll
      for (int nt = 0; nt < 4; ++nt) {
        const int n = n0 + wn + (nt << 4) + (lg << 2);
        const float4 b4 = *(const float4*)(d.bias + n);
        kv[mt][nt][0] = acc[mt][nt][0] + b4.x;
        kv[mt][nt][1] = acc[mt][nt][1] + b4.y;
        kv[mt][nt][2] = acc[mt][nt][2] + b4.z;
        kv[mt][nt][3] = acc[mt][nt][3] + b4.w;
        #pragma unroll
        for (int j = 0; j < 4; ++j) ss += kv[mt][nt][j] * kv[mt][nt][j];
      }
      ss += __shfl_xor(ss, 16);
      ss += __shfl_xor(ss, 32);
      inv[mt] = 1.0 / sqrt((double)ss);
    }
    #pragma unroll
    for (int mt = 0; mt < 2; ++mt) {
      const int l = (m0 + wm + (mt << 4) + lr) & (NL - 1);
      short* kp = d.Kbf + (((size_t)bh * NL + l) << 6);
      #pragma unroll
      for (int nt = 0; nt < 4; ++nt) {
        const int dd = (nt << 4) + (lg << 2);
        bf16x4 o;
        #pragma unroll
        for (int j = 0; j < 4; ++j) o[j] = f2bf(kv[mt][nt][j]);
        *(bf16x4*)(kp + dd) = o;
      }
    }
    #pragma unroll
    for (int nt = 0; nt < 4; ++nt) {
      double p[4];
      #pragma unroll
      for (int j = 0; j < 4; ++j) {
        p[j] = (double)kv[0][nt][j] * inv[0] + (double)kv[1][nt][j] * inv[1];
        p[j] += __shfl_xor(p[j], 1);
        p[j] += __shfl_xor(p[j], 2);
        p[j] += __shfl_xor(p[j], 4);
        p[j] += __shfl_xor(p[j], 8);
      }
      if (lr == 0) {
        const int dd = (nt << 4) + (lg << 2);
        double* kp = d.kpart + ((((size_t)bh << 6) + seg) << 6) + dd;
        kp[0] = p[0]; kp[1] = p[1]; kp[2] = p[2]; kp[3] = p[3];
      }
    }
  } else {
    #pragma unroll
    for (int nt = 0; nt < 4; ++nt) {
      const int n = n0 + wn + (nt << 4) + (lg << 2);
      const float4 b4 = *(const float4*)(d.bias + n);
      #pragma unroll
      for (int mt = 0; mt < 4; ++mt) {
        f32x4 a = acc[mt][nt];
        a[0] += b4.x; a[1] += b4.y; a[2] += b4.z; a[3] += b4.w;
        const int m = m0 + wm + (mt << 4) + lr;
        // scatter into (B,H,L,D)
        const int bb = m >> 11, ll = m & (NL - 1);
        const int hh = n >> 6, dd = n & 63;
        *(f32x4*)(d.C + (((size_t)(bb*NH + hh)*NL + ll) << 6) + dd) = a;
      }
    }
  }
}

// ---------------------------------------------------------------- O projection GEMM (X gathered from Csel via invsel)
// 512 blocks; split-K halves interleaved per CU. Full tile only.
struct OselArgs {
  const short* Xa; const short* Xb;
  const short* Wa; const short* Wb;
  float* C0; float* C1;            // half 0 -> C0 (steps 0..24), half 1 -> C1 (24..48)
  const int* invsel;
};

__global__ __launch_bounds__(256, 3) void gemm_osel_k(OselArgs ar) {
  __shared__ short As[128*64];   // 16 KB
  __shared__ short Bs[128*64];   // 16 KB
  __shared__ int utbl[2048];     // 8 KB
  const int fid = blockIdx.x;
  const int xcd = fid & 7, jd = fid >> 3;
  const int zi = jd & 1;
  const int o = (xcd << 5) + (jd >> 1);
  const int bx = o & 7, by = o >> 3;
  const int sbeg = zi ? 24 : 0, send = zi ? 48 : 24;
  float* C = zi ? ar.C1 : ar.C0;
  const int tid = threadIdx.x;
  const int wv = tid >> 6, L = tid & 63;
  const int lr = L & 15, lg = L >> 4;
  const int n0 = bx << 7, m0 = by << 7;
  const int wm = (wv >> 1) << 6, wn = (wv & 1) << 6;
  const int sr = tid >> 3, ssl = tid & 7;
  const int b2 = by >> 4;

  #pragma unroll
  for (int e = 0; e < 8; ++e) {
    const int idx = (tid << 3) + e;             // 0..2047
    const int row = idx >> 4, h = idx & 15;
    utbl[idx] = ar.invsel[((((size_t)b2 << 4) + h) << 11) + ((m0 + row) & (NL - 1))];
  }
  __syncthreads();

  f32x4 acc[4][4];
  #pragma unroll
  for (int i = 0; i < 4; ++i)
    #pragma unroll
    for (int j = 0; j < 4; ++j) acc[i][j] = (f32x4){0.f,0.f,0.f,0.f};

  for (int step = sbeg; step < send; ++step) {
    const int c = step >> 4, kk = (step & 15) << 6;
    const short* Xg = (c == 1) ? ar.Xa : (c == 2 ? ar.Xb : ar.Xa);
    const short* Wg = (c == 1) ? ar.Wb : ar.Wa;   // c0:(a,a) c1:(a,b) c2:(b,a)
    const short* Xs = (c == 2) ? ar.Xb : ar.Xa;
    #pragma unroll
    for (int j = 0; j < 4; ++j) {
      const int row = (j << 5) + sr;
      const int slot = (ssl ^ (row & 7)) << 3;
      const int h = step & 15;                  // one head per 64-wide step
      const int u = utbl[(row << 4) + h];
      gload16(Xs + (((size_t)((b2 << 4) + h) * NUP + u) << 6) + slot,
              As + (j << 11) + (tid << 3));
      gload16(Wg + (size_t)(n0 + row) * NDM + kk + slot, Bs + (j << 11) + (tid << 3));
    }
    (void)Xg;
    __syncthreads();
    #pragma unroll
    for (int c2 = 0; c2 < 2; ++c2) {
      const int sl = (((c2 << 2) + lg) ^ (lr & 7)) << 3;
      bf16x8 af[4], bfr[4];
      #pragma unroll
      for (int t = 0; t < 4; ++t) {
        af[t]  = *(const bf16x8*)(As + ((wm + (t << 4) + lr) << 6) + sl);
        bfr[t] = *(const bf16x8*)(Bs + ((wn + (t << 4) + lr) << 6) + sl);
      }
      #pragma unroll
      for (int mt = 0; mt < 4; ++mt)
        #pragma unroll
        for (int nt = 0; nt < 4; ++nt)
          acc[mt][nt] = __builtin_amdgcn_mfma_f32_16x16x32_bf16(bfr[nt], af[mt], acc[mt][nt], 0, 0, 0);
    }
    __syncthreads();
  }

  #pragma unroll
  for (int nt = 0; nt < 4; ++nt) {
    const int n = n0 + wn + (nt << 4) + (lg << 2);
    #pragma unroll
    for (int mt = 0; mt < 4; ++mt) {
      const int m = m0 + wm + (mt << 4) + lr;
      *(f32x4*)(C + ((size_t)m << 10) + n) = acc[mt][nt];
    }
  }
}

// ---------------------------------------------------------------- wtilde (+inline kbar reduce): wt[bh][j] f32, s0[bh] f64
__global__ __launch_bounds__(256) void wtilde_k(const float* __restrict__ Wq,
                                                const float* __restrict__ bq,
                                                const double* __restrict__ kpart,
                                                float* __restrict__ wt,
                                                double* __restrict__ s0) {
  __shared__ double kb[64];
  const int bh = blockIdx.x, h = bh & 15;
  const int tid = threadIdx.x;
  if (tid < 64) {
    double s = 0.0;
    #pragma unroll
    for (int seg = 0; seg < 64; ++seg)
      s += kpart[((((size_t)bh << 6) + seg) << 6) + tid];
    kb[tid] = s * (1.0 / NL);
  }
  __syncthreads();
  const int j = (blockIdx.y << 8) + tid;
  double a = 0.0;
  #pragma unroll 8
  for (int d = 0; d < 64; ++d)
    a += (double)Wq[(((size_t)((h << 6) + d)) << 10) + j] * kb[d];
  wt[((size_t)bh << 10) + j] = (float)a;
  if (blockIdx.y == 0 && tid < 64) {
    double p = (double)bq[(h << 6) + tid] * kb[tid];
    #pragma unroll
    for (int off = 32; off > 0; off >>= 1) p += __shfl_xor(p, off);
    if (tid == 0) s0[bh] = p;
  }
}

// ---------------------------------------------------------------- fused dotq+msq: ms[bh][l] = (x.wt + s0)/|q|
__global__ __launch_bounds__(256) void dotqms_k(const float* __restrict__ x,
                                                const float* __restrict__ Qb,
                                                const float* __restrict__ wt,
                                                const double* __restrict__ s0,
                                                float* __restrict__ ms) {
  __shared__ float xs[1024];
  __shared__ double sm[16][16];
  __shared__ double sq[16][16];
  const int r = blockIdx.x, b = r >> 11, l = r & (NL - 1);
  const int tid = threadIdx.x;
  ((float4*)xs)[tid] = ((const float4*)(x + ((size_t)r << 10)))[tid];
  __syncthreads();
  const int h = tid >> 4, t = tid & 15;
  const float* w = wt + ((size_t)((b << 4) + h) << 10);
  double a = 0.0;
  #pragma unroll 8
  for (int i = 0; i < 64; ++i) {
    const int j = t + (i << 4);
    a += (double)xs[j] * (double)w[j];
  }
  sm[h][t] = a;
  const float4 qv = *(const float4*)(Qb + (((size_t)((b << 4) + h) * NL + l) << 6) + (t << 2));
  sq[h][t] = (double)qv.x*qv.x + (double)qv.y*qv.y + (double)qv.z*qv.z + (double)qv.w*qv.w;
  __syncthreads();
  if (tid < 16) {
    double s = 0.0, ssq = 0.0;
    #pragma unroll
    for (int t2 = 0; t2 < 16; ++t2) { s += sm[tid][t2]; ssq += sq[tid][t2]; }
    ms[(((size_t)(b << 4) + tid) << 11) + l] = (float)((s + s0[(b << 4) + tid]) / sqrt(ssq));
  }
}

// ---------------------------------------------------------------- rank-based top-NU selection (+ inverse map; pad -> NU)
__global__ __launch_bounds__(256) void select_rank_k(const float* __restrict__ ms,
                                                     int* __restrict__ sel,
                                                     int* __restrict__ invsel) {
  __shared__ unsigned long long keys[NL];
  const int bh = blockIdx.x >> 3, seg = blockIdx.x & 7;
  const int tid = threadIdx.x;
  for (int l = tid; l < NL; l += 256) {
    unsigned u = __float_as_uint(ms[(size_t)bh * NL + l]);
    u = (u & 0x80000000u) ? ~u : (u | 0x80000000u);   // order-preserving map
    keys[l] = ((unsigned long long)u << 32) | (unsigned)(NL - 1 - l);
  }
  __syncthreads();
  const int r = (seg << 8) + tid;
  const unsigned long long mine = keys[r];
  int cnt = 0;
  #pragma unroll 8
  for (int l = 0; l < NL; ++l) cnt += (keys[l] > mine) ? 1 : 0;
  if (cnt < NU) sel[bh*NU + cnt] = r;
  invsel[(size_t)bh * NL + r] = (cnt < NU) ? cnt : NU;  // NU = zeroed pad row
}

// ---------------------------------------------------------------- V (bh,l,d) f32 -> Vt (bh,d,l) bf16
__global__ __launch_bounds__(256) void transpose_v_k(const float* __restrict__ V0,
                                                     short* __restrict__ Vt) {
  __shared__ float Ts[64][65];
  const int bh = blockIdx.x >> 5, lt = blockIdx.x & 31;
  const int l0 = lt << 6, tid = threadIdx.x;
  const int lr = tid >> 2, j = tid & 3;
  const size_t rowo = ((size_t)bh*NL + l0 + lr) << 6;
  #pragma unroll
  for (int s = 0; s < 4; ++s) {
    const int dd = (j + 4*s) << 2;
    const float4 v = *(const float4*)(V0 + rowo + dd);
    Ts[lr][dd+0] = v.x; Ts[lr][dd+1] = v.y; Ts[lr][dd+2] = v.z; Ts[lr][dd+3] = v.w;
  }
  __syncthreads();
  const int d = tid >> 2, lc = (tid & 3) << 4;
  short* dst = Vt + ((size_t)bh*ND + d) * NL + l0 + lc;
  bf16x8 o0, o1;
  #pragma unroll
  for (int i = 0; i < 8; ++i) {
    o0[i] = f2bf(Ts[lc + i][d]);
    o1[i] = f2bf(Ts[lc + 8 + i][d]);
  }
  *(bf16x8*)dst = o0;
  *(bf16x8*)(dst + 8) = o1;
}

// ---------------------------------------------------------------- fused attention with inline Q gather; split bf16 Csel out
__global__ __launch_bounds__(512) void fattn_k(const float* __restrict__ Qb,
                                               const int* __restrict__ sel,
                                               const short* __restrict__ Kbf,
                                               const short* __restrict__ Vt,
                                               short* __restrict__ Ca,
                                               short* __restrict__ Cb) {
  __shared__ short S[32*2048];        // 128 KB, row stride 4096 B
  __shared__ float inv_s[32];
  int bid = blockIdx.x;
  bid = (bid & 7) * 52 + (bid >> 3);  // 416 = 8*52 XCD chunks
  const int m0 = bid << 5;
  const int bh = m0 / NUP;
  const int u0 = m0 - bh * NUP;
  const int tid = threadIdx.x;
  const int w = tid >> 6, L = tid & 63;
  const int lr = L & 15, lg = L >> 4;

  // ---- Q fragments gathered from f32 Qb via sel (pad rows read row 0, discarded)
  bf16x8 qf[2][2];
  #pragma unroll
  for (int mt = 0; mt < 2; ++mt) {
    const int u = u0 + mt*16 + lr;
    const int lq = (u < NU) ? sel[bh*NU + u] : 0;
    const float* qp = Qb + (((size_t)bh*NL + lq) << 6) + lg*8;
    const float4 q0 = *(const float4*)qp;
    const float4 q1 = *(const float4*)(qp + 4);
    const float4 q2 = *(const float4*)(qp + 32);
    const float4 q3 = *(const float4*)(qp + 36);
    qf[mt][0][0]=f2bf(q0.x); qf[mt][0][1]=f2bf(q0.y); qf[mt][0][2]=f2bf(q0.z); qf[mt][0][3]=f2bf(q0.w);
    qf[mt][0][4]=f2bf(q1.x); qf[mt][0][5]=f2bf(q1.y); qf[mt][0][6]=f2bf(q1.z); qf[mt][0][7]=f2bf(q1.w);
    qf[mt][1][0]=f2bf(q2.x); qf[mt][1][1]=f2bf(q2.y); qf[mt][1][2]=f2bf(q2.z); qf[mt][1][3]=f2bf(q2.w);
    qf[mt][1][4]=f2bf(q3.x); qf[mt][1][5]=f2bf(q3.y); qf[mt][1][6]=f2bf(q3.z); qf[mt][1][7]=f2bf(q3.w);
  }
  const int nb = w << 8;
  const short* kb0 = Kbf + (((size_t)bh*NL + nb + lr) << 6) + lg*8;
  #pragma unroll 2
  for (int nt = 0; nt < 16; ++nt) {
    const short* kp = kb0 + ((size_t)nt << 10);
    const bf16x8 kf0 = *(const bf16x8*)kp;
    const bf16x8 kf1 = *(const bf16x8*)(kp + 32);
    #pragma unroll
    for (int mt = 0; mt < 2; ++mt) {
      f32x4 a = {0.f,0.f,0.f,0.f};
      a = __builtin_amdgcn_mfma_f32_16x16x32_bf16(kf0, qf[mt][0], a, 0, 0, 0);
      a = __builtin_amdgcn_mfma_f32_16x16x32_bf16(kf1, qf[mt][1], a, 0, 0, 0);
      const int m = mt*16 + lr;
      bf16x4 o;
      #pragma unroll
      for (int r = 0; r < 4; ++r) o[r] = f2bf(a[r] * 0.125f);
      const int byteoff = (m << 12) + ((((nb + nt*16 + lg*4) << 1)) ^ ((m & 7) << 4));
      *(bf16x4*)((char*)S + byteoff) = o;
    }
  }
  __syncthreads();

  #pragma unroll
  for (int j = 0; j < 4; ++j) {
    const int R = (w << 2) + j;
    char* rowp = (char*)S + (R << 12);
    const int sw = (R & 7) << 4;
    bf16x8 v[4];
    #pragma unroll
    for (int i = 0; i < 4; ++i)
      v[i] = *(const bf16x8*)(rowp + (((L << 6) + (i << 4)) ^ sw));
    float f[32];
    #pragma unroll
    for (int i = 0; i < 4; ++i)
      #pragma unroll
      for (int e = 0; e < 8; ++e) f[i*8+e] = bf2f(v[i][e]);
    float mx = f[0];
    #pragma unroll
    for (int i = 1; i < 32; ++i) mx = fmaxf(mx, f[i]);
    #pragma unroll
    for (int off = 32; off > 0; off >>= 1) mx = fmaxf(mx, __shfl_xor(mx, off));
    float sum = 0.f;
    #pragma unroll
    for (int i = 0; i < 32; ++i) { f[i] = __expf(f[i] - mx); sum += f[i]; }
    #pragma unroll
    for (int off = 32; off > 0; off >>= 1) sum += __shfl_xor(sum, off);
    bf16x8 p[4];
    #pragma unroll
    for (int i = 0; i < 4; ++i)
      #pragma unroll
      for (int e = 0; e < 8; ++e) p[i][e] = f2bf(f[i*8+e]);
    #pragma unroll
    for (int i = 0; i < 4; ++i)
      *(bf16x8*)(rowp + (((L << 6) + (i << 4)) ^ sw)) = p[i];
    if (L == 0) inv_s[R] = 1.f / sum;
  }
  __syncthreads();

  {
    const int mt = w & 1, dt = w >> 1;
    const int m = mt*16 + lr;
    const char* arow = (const char*)S + (m << 12);
    const int sw = (m & 7) << 4;
    const short* vrow = Vt + (((size_t)bh*ND + dt*16 + lr) << 11) + lg*8;
    f32x4 acc0 = {0.f,0.f,0.f,0.f}, acc1 = {0.f,0.f,0.f,0.f};
    for (int k0 = 0; k0 < NL; k0 += 64) {
      const bf16x8 p0 = *(const bf16x8*)(arow + ((((k0 + lg*8) << 1)) ^ sw));
      const bf16x8 p1 = *(const bf16x8*)(arow + ((((k0 + 32 + lg*8) << 1)) ^ sw));
      const bf16x8 v0 = *(const bf16x8*)(vrow + k0);
      const bf16x8 v1 = *(const bf16x8*)(vrow + k0 + 32);
      acc0 = __builtin_amdgcn_mfma_f32_16x16x32_bf16(p0, v0, acc0, 0, 0, 0);
      acc1 = __builtin_amdgcn_mfma_f32_16x16x32_bf16(p1, v1, acc1, 0, 0, 0);
    }
    const int ub = u0 + mt*16 + (lg << 2);
    #pragma unroll
    for (int r = 0; r < 4; ++r) {
      float val = (acc0[r] + acc1[r]) * inv_s[mt*16 + (lg << 2) + r];
      if (ub + r >= NU) val = 0.f;                 // zero pad rows (incl. row NU)
      const size_t off = (((size_t)m0 + mt*16 + (lg << 2) + r) << 6) + dt*16 + lr;
      const short A = f2bf(val);
      Ca[off] = A;
      Cb[off] = f2bf(val - bf2f(A));
    }
  }
}

// ---------------------------------------------------------------- out += P1 + bias
__global__ __launch_bounds__(256) void oadd_k(float* __restrict__ out,
                                              const float* __restrict__ P1,
                                              const float* __restrict__ bo) {
  const size_t i4 = (size_t)blockIdx.x * 256 + threadIdx.x;
  const size_t i = i4 << 2;
  float4 a = *(float4*)(out + i);
  const float4 b = *(const float4*)(P1 + i);
  const float4 c = *(const float4*)(bo + ((i4 & 255) << 2));
  a.x += b.x + c.x; a.y += b.y + c.y; a.z += b.z + c.z; a.w += b.w + c.w;
  *(float4*)(out + i) = a;
}

// ---------------------------------------------------------------- launch
extern "C" void kernel_launch(void* const* d_in, const int* in_sizes, int n_in,
                              void* d_out, int out_size, void* d_ws, size_t ws_size,
                              hipStream_t stream)
{
  (void)in_sizes; (void)n_in; (void)out_size; (void)ws_size;
  const float* queries = (const float*)d_in[0];
  const float* keys    = (const float*)d_in[1];
  const float* values  = (const float*)d_in[2];
  const float* Wq = (const float*)d_in[3];  const float* bq = (const float*)d_in[4];
  const float* Wk = (const float*)d_in[5];  const float* bk = (const float*)d_in[6];
  const float* Wv = (const float*)d_in[7];  const float* bv = (const float*)d_in[8];
  const float* Wo = (const float*)d_in[9];  const float* bo = (const float*)d_in[10];
  float* out = (float*)d_out;

  char* base = (char*)d_ws;
  #define MB(x) ((size_t)(x) << 20)

  short* Qa   = (short*)(base + MB(0));    // 8 MiB  -> Vt after mega
  short* Qb2  = (short*)(base + MB(8));    // 8 MiB  -> CselA/CselB after mega
  short* Ka   = (short*)(base + MB(16));
  short* Kb2  = (short*)(base + MB(24));
  short* Kc   = (short*)(base + MB(32));
  short* Vbf  = (short*)(base + MB(40));
  float* Qb   = (float*)(base + MB(48));   // 16 MiB -> P1o after fattn
  short* Kbf  = (short*)(base + MB(64));   // 8 MiB
  short* Wqa  = (short*)(base + MB(72));
  short* Wqb  = (short*)(base + MB(74));
  short* Wka  = (short*)(base + MB(76));
  short* Wkb  = (short*)(base + MB(78));
  short* Wkc  = (short*)(base + MB(80));
  short* Wvbf = (short*)(base + MB(82));
  short* Woa  = (short*)(base + MB(84));
  short* Wob  = (short*)(base + MB(86));
  char* sm = base + MB(88);
  double* kpart  = (double*)sm;  sm += 1048576;   // [32][64][64] f64
  float*  wt     = (float*)sm;   sm += 131072;    // [32][1024] f32
  double* s0     = (double*)sm;  sm += 512;
  float*  msb    = (float*)sm;   sm += 262144;
  int*    sel    = (int*)sm;     sm += 65536;
  int*    invsel = (int*)sm;     sm += 262144;

  // time-multiplexed aliases
  float* Vp    = out;                       // V projection scratch (fully overwritten later)
  short* Vt    = Qa;                        // after mega
  short* CselA = Qb2;                       // 1.625 MiB
  short* CselB = (short*)(base + MB(10));   // 1.625 MiB
  float* P1o   = Qb;                        // after fattn

  // ---- 1: all splits in one launch (inputs + weights)
  {
    SplitArgs a;
    a.d[0] = {queries, Qa, Qb2, nullptr, 2, 2048};
    a.d[1] = {keys,    Ka, Kb2, Kc,      3, 2048};
    a.d[2] = {values,  Vbf, nullptr, nullptr, 1, 2048};
    a.d[3] = {Wq, Wqa, Wqb, nullptr, 2, 512};
    a.d[4] = {Wk, Wka, Wkb, Wkc,     3, 512};
    a.d[5] = {Wv, Wvbf, nullptr, nullptr, 1, 512};
    a.d[6] = {Wo, Woa, Wob, nullptr, 2, 512};
    msplit_k<<<dim3(2048,1,7), 256, 0, stream>>>(a);
  }
  // ---- 2: balanced mega GEMM: Q(3-prod, full tile) + K(6-prod, half tile,
  //         fused epilogue) + V(1-prod, full tile); 1024 blocks, [K,Q,K,V]/CU
  {
    GemmArgs g;
    g.d[0] = {{Qa,Qb2,Qa}, {Wqa,Wqb,Wqa}, bq, Qb, nullptr, nullptr, 0, 48, 0};
    g.d[1] = {{Ka,Kb2,Kc}, {Wka,Wkb,Wkc}, bk, nullptr, Kbf, kpart, 0, 96, 1};
    g.d[2] = {{Vbf,Vbf,Vbf}, {Wvbf,Wvbf,Wvbf}, bv, Vp, nullptr, nullptr, 0, 16, 0};
    gemm_mega_k<<<1024, 256, 0, stream>>>(g);
  }
  // ---- 3-6: V transpose + ranking chain
  transpose_v_k<<<NBH*32, 256, 0, stream>>>(Vp, Vt);
  wtilde_k<<<dim3(NBH,4), 256, 0, stream>>>(Wq, bq, kpart, wt, s0);
  dotqms_k<<<NROWS, 256, 0, stream>>>(queries, Qb, wt, s0, msb);
  select_rank_k<<<NBH*8, 256, 0, stream>>>(msb, sel, invsel);

  // ---- 7: fused attention (inline Q gather; split bf16 Csel; pad rows zeroed)
  fattn_k<<<MTOT/32, 512, 0, stream>>>(Qb, sel, Kbf, Vt, CselA, CselB);

  // ---- 8: output projection (X gathered from Csel via invsel), split-K 2-way
  {
    OselArgs oa = {CselA, CselB, Woa, Wob, out, P1o, invsel};
    gemm_osel_k<<<512, 256, 0, stream>>>(oa);
  }
  // ---- 9: combine + bias
  oadd_k<<<4096, 256, 0, stream>>>(out, P1o, bo);
}

// Round 11
// 279.389 us; speedup vs baseline: 1.9754x; 1.2834x over previous
//
#include <hip/hip_runtime.h>
#include <math.h>

// Problem constants (fixed by setup_inputs)
#define NB 2
#define NL 2048
#define NH 16
#define ND 64
#define NDM 1024
#define NU 409                  // max(1, 2048 // 5)
#define NUP 416                 // NU padded to multiple of 32; 416 = 26*16 = 13*32
#define NBH (NB*NH)             // 32
#define NROWS (NB*NL)           // 4096
#define NRTOT (NB*NH*NL)        // 65536
#define MTOT (NBH*NUP)          // 13312

typedef short bf16x8 __attribute__((ext_vector_type(8)));
typedef short bf16x4 __attribute__((ext_vector_type(4)));
typedef float f32x4  __attribute__((ext_vector_type(4)));

__device__ __forceinline__ short f2bf(float x) {   // RNE f32 -> bf16
  unsigned u = __float_as_uint(x);
  return (short)((u + 0x7FFFu + ((u >> 16) & 1u)) >> 16);
}
__device__ __forceinline__ float bf2f(short s) {
  return __uint_as_float(((unsigned)(unsigned short)s) << 16);
}

__device__ __forceinline__ void gload16(const short* g, short* l) {
  __builtin_amdgcn_global_load_lds(
      (const __attribute__((address_space(1))) void*)g,
      (__attribute__((address_space(3))) void*)l, 16, 0, 0);
}

// ---------------------------------------------------------------- multi-tensor f32 -> bf16 splits
struct SplitDesc { const float* in; short* a; short* b; short* c; int nc; int nblk; };
struct SplitArgs { SplitDesc d[7]; };

__global__ __launch_bounds__(256) void msplit_k(SplitArgs args) {
  const SplitDesc d = args.d[blockIdx.z];
  if ((int)blockIdx.x >= d.nblk) return;
  const size_t i = (size_t)blockIdx.x * 256 + threadIdx.x;
  const float4 x0 = ((const float4*)d.in)[2*i];
  const float4 x1 = ((const float4*)d.in)[2*i + 1];
  float x[8] = {x0.x,x0.y,x0.z,x0.w, x1.x,x1.y,x1.z,x1.w};
  bf16x8 va, vb, vc;
  #pragma unroll
  for (int j = 0; j < 8; ++j) {
    const short A = f2bf(x[j]);
    const float r1 = x[j] - bf2f(A);
    const short B = f2bf(r1);
    va[j] = A; vb[j] = B;
    vc[j] = f2bf(r1 - bf2f(B));
  }
  *(bf16x8*)(d.a + 8*i) = va;
  if (d.nc >= 2) *(bf16x8*)(d.b + 8*i) = vb;
  if (d.nc == 3) *(bf16x8*)(d.c + 8*i) = vc;
}

// ---------------------------------------------------------------- mega projection GEMM (Q/K0/K1/V), full 128x128 tiles
// BK=64, 4 waves 2x2, wave 64x64 = 4x4 16x16 frags.
// chunk pairs (c=step>>4): c0 (a,a), c1 (a,b), c2 (b,a), c3 (a,c), c4 (c,a), c5 (b,b)
// LDS: linear dest for global_load_lds; SOURCE k-slot pre-swizzled s^=(row&7);
// fragment reads apply the same XOR (rule 21).
// 1024 blocks; fid&7 = XCD, jd&3 = desc -> each CU hosts {Q,K0,K1,V}; all
// full-tile 48-step-class blocks (V drains at 16 leaving 3/CU, round-7 regime).
// mode 0: SC-scatter f32 + bias (Q)
// mode 1: SC-scatter f32, no bias (K split-K partials)
// mode 2: fused V epilogue: +bias, transpose-scatter bf16 into Vt (bh,d,l)
struct GemmDesc {
  const short* X[3];
  const short* W[3];
  const float* bias;    // may be null
  float* C;             // modes 0/1
  short* Vt;            // mode 2
  int sbeg, send;       // step range; one step = 64 k-elems; chunk = step>>4
  int mode;
};
struct GemmArgs { GemmDesc d[4]; };

__global__ __launch_bounds__(256, 3) void gemm_mega_k(GemmArgs args) {
  __shared__ short As[128*64];   // 16 KB
  __shared__ short Bs[128*64];   // 16 KB
  const int fid = blockIdx.x;
  const int xcd = fid & 7, jd = fid >> 3;   // jd 0..127
  const int s = jd & 3, jj = jd >> 2;       // desc s; tile jj 0..31
  const int tile = (xcd << 5) + jj;         // 0..255
  const int bx = tile & 7, by = tile >> 3;
  const GemmDesc d = args.d[s];
  const int tid = threadIdx.x;
  const int wv = tid >> 6, L = tid & 63;
  const int lr = L & 15, lg = L >> 4;
  const int n0 = bx << 7, m0 = by << 7;
  const int wm = (wv >> 1) << 6, wn = (wv & 1) << 6;
  const int sr = tid >> 3, ssl = tid & 7;

  f32x4 acc[4][4];
  #pragma unroll
  for (int i = 0; i < 4; ++i)
    #pragma unroll
    for (int j = 0; j < 4; ++j) acc[i][j] = (f32x4){0.f,0.f,0.f,0.f};

  for (int step = d.sbeg; step < d.send; ++step) {
    const int c = step >> 4, kk = (step & 15) << 6;
    const short *Xg, *Wg;
    switch (c) {
      case 0:  Xg = d.X[0]; Wg = d.W[0]; break;
      case 1:  Xg = d.X[0]; Wg = d.W[1]; break;
      case 2:  Xg = d.X[1]; Wg = d.W[0]; break;
      case 3:  Xg = d.X[0]; Wg = d.W[2]; break;
      case 4:  Xg = d.X[2]; Wg = d.W[0]; break;
      default: Xg = d.X[1]; Wg = d.W[1]; break;
    }
    #pragma unroll
    for (int j = 0; j < 4; ++j) {
      const int row = (j << 5) + sr;
      const int slot = (ssl ^ (row & 7)) << 3;   // pre-swizzled k-slot
      gload16(Xg + (size_t)(m0 + row) * NDM + kk + slot, As + (j << 11) + (tid << 3));
      gload16(Wg + (size_t)(n0 + row) * NDM + kk + slot, Bs + (j << 11) + (tid << 3));
    }
    __syncthreads();
    #pragma unroll
    for (int c2 = 0; c2 < 2; ++c2) {
      const int sl = (((c2 << 2) + lg) ^ (lr & 7)) << 3;
      bf16x8 af[4], bfr[4];
      #pragma unroll
      for (int t = 0; t < 4; ++t) {
        af[t]  = *(const bf16x8*)(As + ((wm + (t << 4) + lr) << 6) + sl);
        bfr[t] = *(const bf16x8*)(Bs + ((wn + (t << 4) + lr) << 6) + sl);
      }
      #pragma unroll
      for (int mt = 0; mt < 4; ++mt)
        #pragma unroll
        for (int nt = 0; nt < 4; ++nt)
          acc[mt][nt] = __builtin_amdgcn_mfma_f32_16x16x32_bf16(bfr[nt], af[mt], acc[mt][nt], 0, 0, 0);
    }
    __syncthreads();
  }

  if (d.mode == 2) {
    // fused V epilogue: +bias, transpose-scatter bf16 into Vt[bh][d][l]
    #pragma unroll
    for (int nt = 0; nt < 4; ++nt) {
      const int n = n0 + wn + (nt << 4) + (lg << 2);
      const float4 b4 = *(const float4*)(d.bias + n);
      const int h = n >> 6, db = n & 63;
      #pragma unroll
      for (int mt = 0; mt < 4; ++mt) {
        const int m = m0 + wm + (mt << 4) + lr;
        const int bb = m >> 11, ll = m & (NL - 1);
        short* vt = d.Vt + (((size_t)(((bb << 4) + h) << 6) + db) << 11) + ll;
        vt[0]                 = f2bf(acc[mt][nt][0] + b4.x);
        vt[(size_t)1 << 11]   = f2bf(acc[mt][nt][1] + b4.y);
        vt[(size_t)2 << 11]   = f2bf(acc[mt][nt][2] + b4.z);
        vt[(size_t)3 << 11]   = f2bf(acc[mt][nt][3] + b4.w);
      }
    }
  } else {
    #pragma unroll
    for (int nt = 0; nt < 4; ++nt) {
      const int n = n0 + wn + (nt << 4) + (lg << 2);
      float4 b4 = make_float4(0.f, 0.f, 0.f, 0.f);
      if (d.bias) b4 = *(const float4*)(d.bias + n);
      #pragma unroll
      for (int mt = 0; mt < 4; ++mt) {
        f32x4 a = acc[mt][nt];
        a[0] += b4.x; a[1] += b4.y; a[2] += b4.z; a[3] += b4.w;
        const int m = m0 + wm + (mt << 4) + lr;
        const int bb = m >> 11, ll = m & (NL - 1);
        const int hh = n >> 6, dd = n & 63;
        *(f32x4*)(d.C + (((size_t)(bb*NH + hh)*NL + ll) << 6) + dd) = a;
      }
    }
  }
}

// ---------------------------------------------------------------- K combine: Kp0+Kp1+bias -> Kbf bf16, khat partials
__global__ __launch_bounds__(256) void combine_k(const float* __restrict__ Kp0,
                                                 const float* __restrict__ Kp1,
                                                 const float* __restrict__ bk,
                                                 short* __restrict__ Kbf,
                                                 double* __restrict__ kpart) {
  __shared__ double sm[4][64];
  const int bh = blockIdx.x >> 5, seg = blockIdx.x & 31;
  const int g = threadIdx.x >> 6, d = threadIdx.x & 63;
  const int h = bh & 15;
  const float bias = bk[(h << 6) + d];
  double acc = 0.0;
  #pragma unroll 4
  for (int i = 0; i < 16; ++i) {
    const int l = (seg << 6) + (i << 2) + g;
    const size_t o = (((size_t)bh * NL + l) << 6) + d;
    const float k = Kp0[o] + Kp1[o] + bias;
    float ss = k * k;
    #pragma unroll
    for (int off = 32; off > 0; off >>= 1) ss += __shfl_xor(ss, off);
    const double inv = 1.0 / sqrt((double)ss);
    Kbf[o] = f2bf(k);
    acc += (double)k * inv;
  }
  sm[g][d] = acc;
  __syncthreads();
  if (threadIdx.x < 64)
    kpart[((((size_t)bh << 5) + seg) << 6) + threadIdx.x] =
        sm[0][threadIdx.x] + sm[1][threadIdx.x] + sm[2][threadIdx.x] + sm[3][threadIdx.x];
}

// ---------------------------------------------------------------- wtilde (+inline kbar reduce): wt[bh][j] f32, s0[bh] f64
__global__ __launch_bounds__(256) void wtilde_k(const float* __restrict__ Wq,
                                                const float* __restrict__ bq,
                                                const double* __restrict__ kpart,
                                                float* __restrict__ wt,
                                                double* __restrict__ s0) {
  __shared__ double kb[64];
  const int bh = blockIdx.x, h = bh & 15;
  const int tid = threadIdx.x;
  if (tid < 64) {
    double s = 0.0;
    #pragma unroll
    for (int seg = 0; seg < 32; ++seg)
      s += kpart[((((size_t)bh << 5) + seg) << 6) + tid];
    kb[tid] = s * (1.0 / NL);
  }
  __syncthreads();
  const int j = (blockIdx.y << 8) + tid;
  double a = 0.0;
  #pragma unroll 8
  for (int d = 0; d < 64; ++d)
    a += (double)Wq[(((size_t)((h << 6) + d)) << 10) + j] * kb[d];
  wt[((size_t)bh << 10) + j] = (float)a;
  if (blockIdx.y == 0 && tid < 64) {
    double p = (double)bq[(h << 6) + tid] * kb[tid];
    #pragma unroll
    for (int off = 32; off > 0; off >>= 1) p += __shfl_xor(p, off);
    if (tid == 0) s0[bh] = p;
  }
}

// ---------------------------------------------------------------- fused dotq+msq: ms[bh][l] = (x.wt + s0)/|q|
__global__ __launch_bounds__(256) void dotqms_k(const float* __restrict__ x,
                                                const float* __restrict__ Qb,
                                                const float* __restrict__ wt,
                                                const double* __restrict__ s0,
                                                float* __restrict__ ms) {
  __shared__ float xs[1024];
  __shared__ double sm[16][16];
  __shared__ double sq[16][16];
  const int r = blockIdx.x, b = r >> 11, l = r & (NL - 1);
  const int tid = threadIdx.x;
  ((float4*)xs)[tid] = ((const float4*)(x + ((size_t)r << 10)))[tid];
  __syncthreads();
  const int h = tid >> 4, t = tid & 15;
  const float* w = wt + ((size_t)((b << 4) + h) << 10);
  double a = 0.0;
  #pragma unroll 8
  for (int i = 0; i < 64; ++i) {
    const int j = t + (i << 4);
    a += (double)xs[j] * (double)w[j];
  }
  sm[h][t] = a;
  const float4 qv = *(const float4*)(Qb + (((size_t)((b << 4) + h) * NL + l) << 6) + (t << 2));
  sq[h][t] = (double)qv.x*qv.x + (double)qv.y*qv.y + (double)qv.z*qv.z + (double)qv.w*qv.w;
  __syncthreads();
  if (tid < 16) {
    double s = 0.0, ssq = 0.0;
    #pragma unroll
    for (int t2 = 0; t2 < 16; ++t2) { s += sm[tid][t2]; ssq += sq[tid][t2]; }
    ms[(((size_t)(b << 4) + tid) << 11) + l] = (float)((s + s0[(b << 4) + tid]) / sqrt(ssq));
  }
}

// ---------------------------------------------------------------- rank-based top-NU selection (+ inverse map; pad -> NU)
__global__ __launch_bounds__(256) void select_rank_k(const float* __restrict__ ms,
                                                     int* __restrict__ sel,
                                                     int* __restrict__ invsel) {
  __shared__ unsigned long long keys[NL];
  const int bh = blockIdx.x >> 3, seg = blockIdx.x & 7;
  const int tid = threadIdx.x;
  for (int l = tid; l < NL; l += 256) {
    unsigned u = __float_as_uint(ms[(size_t)bh * NL + l]);
    u = (u & 0x80000000u) ? ~u : (u | 0x80000000u);   // order-preserving map
    keys[l] = ((unsigned long long)u << 32) | (unsigned)(NL - 1 - l);
  }
  __syncthreads();
  const int r = (seg << 8) + tid;
  const unsigned long long mine = keys[r];
  int cnt = 0;
  #pragma unroll 8
  for (int l = 0; l < NL; ++l) cnt += (keys[l] > mine) ? 1 : 0;
  if (cnt < NU) sel[bh*NU + cnt] = r;
  invsel[(size_t)bh * NL + r] = (cnt < NU) ? cnt : NU;  // NU = zeroed pad row
}

// ---------------------------------------------------------------- fused attention with inline Q gather; split bf16 Csel out
__global__ __launch_bounds__(512) void fattn_k(const float* __restrict__ Qb,
                                               const int* __restrict__ sel,
                                               const short* __restrict__ Kbf,
                                               const short* __restrict__ Vt,
                                               short* __restrict__ Ca,
                                               short* __restrict__ Cb) {
  __shared__ short S[32*2048];        // 128 KB, row stride 4096 B
  __shared__ float inv_s[32];
  int bid = blockIdx.x;
  bid = (bid & 7) * 52 + (bid >> 3);  // 416 = 8*52 XCD chunks
  const int m0 = bid << 5;
  const int bh = m0 / NUP;
  const int u0 = m0 - bh * NUP;
  const int tid = threadIdx.x;
  const int w = tid >> 6, L = tid & 63;
  const int lr = L & 15, lg = L >> 4;

  // ---- Q fragments gathered from f32 Qb via sel (pad rows read row 0, discarded)
  bf16x8 qf[2][2];
  #pragma unroll
  for (int mt = 0; mt < 2; ++mt) {
    const int u = u0 + mt*16 + lr;
    const int lq = (u < NU) ? sel[bh*NU + u] : 0;
    const float* qp = Qb + (((size_t)bh*NL + lq) << 6) + lg*8;
    const float4 q0 = *(const float4*)qp;
    const float4 q1 = *(const float4*)(qp + 4);
    const float4 q2 = *(const float4*)(qp + 32);
    const float4 q3 = *(const float4*)(qp + 36);
    qf[mt][0][0]=f2bf(q0.x); qf[mt][0][1]=f2bf(q0.y); qf[mt][0][2]=f2bf(q0.z); qf[mt][0][3]=f2bf(q0.w);
    qf[mt][0][4]=f2bf(q1.x); qf[mt][0][5]=f2bf(q1.y); qf[mt][0][6]=f2bf(q1.z); qf[mt][0][7]=f2bf(q1.w);
    qf[mt][1][0]=f2bf(q2.x); qf[mt][1][1]=f2bf(q2.y); qf[mt][1][2]=f2bf(q2.z); qf[mt][1][3]=f2bf(q2.w);
    qf[mt][1][4]=f2bf(q3.x); qf[mt][1][5]=f2bf(q3.y); qf[mt][1][6]=f2bf(q3.z); qf[mt][1][7]=f2bf(q3.w);
  }
  const int nb = w << 8;
  const short* kb0 = Kbf + (((size_t)bh*NL + nb + lr) << 6) + lg*8;
  #pragma unroll 2
  for (int nt = 0; nt < 16; ++nt) {
    const short* kp = kb0 + ((size_t)nt << 10);
    const bf16x8 kf0 = *(const bf16x8*)kp;
    const bf16x8 kf1 = *(const bf16x8*)(kp + 32);
    #pragma unroll
    for (int mt = 0; mt < 2; ++mt) {
      f32x4 a = {0.f,0.f,0.f,0.f};
      a = __builtin_amdgcn_mfma_f32_16x16x32_bf16(kf0, qf[mt][0], a, 0, 0, 0);
      a = __builtin_amdgcn_mfma_f32_16x16x32_bf16(kf1, qf[mt][1], a, 0, 0, 0);
      const int m = mt*16 + lr;
      bf16x4 o;
      #pragma unroll
      for (int r = 0; r < 4; ++r) o[r] = f2bf(a[r] * 0.125f);
      const int byteoff = (m << 12) + ((((nb + nt*16 + lg*4) << 1)) ^ ((m & 7) << 4));
      *(bf16x4*)((char*)S + byteoff) = o;
    }
  }
  __syncthreads();

  #pragma unroll
  for (int j = 0; j < 4; ++j) {
    const int R = (w << 2) + j;
    char* rowp = (char*)S + (R << 12);
    const int sw = (R & 7) << 4;
    bf16x8 v[4];
    #pragma unroll
    for (int i = 0; i < 4; ++i)
      v[i] = *(const bf16x8*)(rowp + (((L << 6) + (i << 4)) ^ sw));
    float f[32];
    #pragma unroll
    for (int i = 0; i < 4; ++i)
      #pragma unroll
      for (int e = 0; e < 8; ++e) f[i*8+e] = bf2f(v[i][e]);
    float mx = f[0];
    #pragma unroll
    for (int i = 1; i < 32; ++i) mx = fmaxf(mx, f[i]);
    #pragma unroll
    for (int off = 32; off > 0; off >>= 1) mx = fmaxf(mx, __shfl_xor(mx, off));
    float sum = 0.f;
    #pragma unroll
    for (int i = 0; i < 32; ++i) { f[i] = __expf(f[i] - mx); sum += f[i]; }
    #pragma unroll
    for (int off = 32; off > 0; off >>= 1) sum += __shfl_xor(sum, off);
    bf16x8 p[4];
    #pragma unroll
    for (int i = 0; i < 4; ++i)
      #pragma unroll
      for (int e = 0; e < 8; ++e) p[i][e] = f2bf(f[i*8+e]);
    #pragma unroll
    for (int i = 0; i < 4; ++i)
      *(bf16x8*)(rowp + (((L << 6) + (i << 4)) ^ sw)) = p[i];
    if (L == 0) inv_s[R] = 1.f / sum;
  }
  __syncthreads();

  {
    const int mt = w & 1, dt = w >> 1;
    const int m = mt*16 + lr;
    const char* arow = (const char*)S + (m << 12);
    const int sw = (m & 7) << 4;
    const short* vrow = Vt + (((size_t)bh*ND + dt*16 + lr) << 11) + lg*8;
    f32x4 acc0 = {0.f,0.f,0.f,0.f}, acc1 = {0.f,0.f,0.f,0.f};
    for (int k0 = 0; k0 < NL; k0 += 64) {
      const bf16x8 p0 = *(const bf16x8*)(arow + ((((k0 + lg*8) << 1)) ^ sw));
      const bf16x8 p1 = *(const bf16x8*)(arow + ((((k0 + 32 + lg*8) << 1)) ^ sw));
      const bf16x8 v0 = *(const bf16x8*)(vrow + k0);
      const bf16x8 v1 = *(const bf16x8*)(vrow + k0 + 32);
      acc0 = __builtin_amdgcn_mfma_f32_16x16x32_bf16(p0, v0, acc0, 0, 0, 0);
      acc1 = __builtin_amdgcn_mfma_f32_16x16x32_bf16(p1, v1, acc1, 0, 0, 0);
    }
    const int ub = u0 + mt*16 + (lg << 2);
    #pragma unroll
    for (int r = 0; r < 4; ++r) {
      float val = (acc0[r] + acc1[r]) * inv_s[mt*16 + (lg << 2) + r];
      if (ub + r >= NU) val = 0.f;                 // zero pad rows (incl. row NU)
      const size_t off = (((size_t)m0 + mt*16 + (lg << 2) + r) << 6) + dt*16 + lr;
      const short A = f2bf(val);
      Ca[off] = A;
      Cb[off] = f2bf(val - bf2f(A));
    }
  }
}

// ---------------------------------------------------------------- O projection GEMM (X gathered from Csel via invsel)
// 512 blocks; split-K halves interleaved per CU. Full tile only.
struct OselArgs {
  const short* Xa; const short* Xb;
  const short* Wa; const short* Wb;
  float* C0; float* C1;            // half 0 -> C0 (steps 0..24), half 1 -> C1 (24..48)
  const int* invsel;
};

__global__ __launch_bounds__(256, 3) void gemm_osel_k(OselArgs ar) {
  __shared__ short As[128*64];   // 16 KB
  __shared__ short Bs[128*64];   // 16 KB
  __shared__ int utbl[2048];     // 8 KB
  const int fid = blockIdx.x;
  const int xcd = fid & 7, jd = fid >> 3;
  const int zi = jd & 1;
  const int o = (xcd << 5) + (jd >> 1);
  const int bx = o & 7, by = o >> 3;
  const int sbeg = zi ? 24 : 0, send = zi ? 48 : 24;
  float* C = zi ? ar.C1 : ar.C0;
  const int tid = threadIdx.x;
  const int wv = tid >> 6, L = tid & 63;
  const int lr = L & 15, lg = L >> 4;
  const int n0 = bx << 7, m0 = by << 7;
  const int wm = (wv >> 1) << 6, wn = (wv & 1) << 6;
  const int sr = tid >> 3, ssl = tid & 7;
  const int b2 = by >> 4;

  #pragma unroll
  for (int e = 0; e < 8; ++e) {
    const int idx = (tid << 3) + e;             // 0..2047
    const int row = idx >> 4, h = idx & 15;
    utbl[idx] = ar.invsel[((((size_t)b2 << 4) + h) << 11) + ((m0 + row) & (NL - 1))];
  }
  __syncthreads();

  f32x4 acc[4][4];
  #pragma unroll
  for (int i = 0; i < 4; ++i)
    #pragma unroll
    for (int j = 0; j < 4; ++j) acc[i][j] = (f32x4){0.f,0.f,0.f,0.f};

  for (int step = sbeg; step < send; ++step) {
    const int c = step >> 4, kk = (step & 15) << 6;
    const short* Wg = (c == 1) ? ar.Wb : ar.Wa;   // c0:(a,a) c1:(a,b) c2:(b,a)
    const short* Xs = (c == 2) ? ar.Xb : ar.Xa;
    #pragma unroll
    for (int j = 0; j < 4; ++j) {
      const int row = (j << 5) + sr;
      const int slot = (ssl ^ (row & 7)) << 3;
      const int h = step & 15;                  // one head per 64-wide step
      const int u = utbl[(row << 4) + h];
      gload16(Xs + (((size_t)((b2 << 4) + h) * NUP + u) << 6) + slot,
              As + (j << 11) + (tid << 3));
      gload16(Wg + (size_t)(n0 + row) * NDM + kk + slot, Bs + (j << 11) + (tid << 3));
    }
    __syncthreads();
    #pragma unroll
    for (int c2 = 0; c2 < 2; ++c2) {
      const int sl = (((c2 << 2) + lg) ^ (lr & 7)) << 3;
      bf16x8 af[4], bfr[4];
      #pragma unroll
      for (int t = 0; t < 4; ++t) {
        af[t]  = *(const bf16x8*)(As + ((wm + (t << 4) + lr) << 6) + sl);
        bfr[t] = *(const bf16x8*)(Bs + ((wn + (t << 4) + lr) << 6) + sl);
      }
      #pragma unroll
      for (int mt = 0; mt < 4; ++mt)
        #pragma unroll
        for (int nt = 0; nt < 4; ++nt)
          acc[mt][nt] = __builtin_amdgcn_mfma_f32_16x16x32_bf16(bfr[nt], af[mt], acc[mt][nt], 0, 0, 0);
    }
    __syncthreads();
  }

  #pragma unroll
  for (int nt = 0; nt < 4; ++nt) {
    const int n = n0 + wn + (nt << 4) + (lg << 2);
    #pragma unroll
    for (int mt = 0; mt < 4; ++mt) {
      const int m = m0 + wm + (mt << 4) + lr;
      *(f32x4*)(C + ((size_t)m << 10) + n) = acc[mt][nt];
    }
  }
}

// ---------------------------------------------------------------- out += P1 + bias
__global__ __launch_bounds__(256) void oadd_k(float* __restrict__ out,
                                              const float* __restrict__ P1,
                                              const float* __restrict__ bo) {
  const size_t i4 = (size_t)blockIdx.x * 256 + threadIdx.x;
  const size_t i = i4 << 2;
  float4 a = *(float4*)(out + i);
  const float4 b = *(const float4*)(P1 + i);
  const float4 c = *(const float4*)(bo + ((i4 & 255) << 2));
  a.x += b.x + c.x; a.y += b.y + c.y; a.z += b.z + c.z; a.w += b.w + c.w;
  *(float4*)(out + i) = a;
}

// ---------------------------------------------------------------- launch
extern "C" void kernel_launch(void* const* d_in, const int* in_sizes, int n_in,
                              void* d_out, int out_size, void* d_ws, size_t ws_size,
                              hipStream_t stream)
{
  (void)in_sizes; (void)n_in; (void)out_size; (void)ws_size;
  const float* queries = (const float*)d_in[0];
  const float* keys    = (const float*)d_in[1];
  const float* values  = (const float*)d_in[2];
  const float* Wq = (const float*)d_in[3];  const float* bq = (const float*)d_in[4];
  const float* Wk = (const float*)d_in[5];  const float* bk = (const float*)d_in[6];
  const float* Wv = (const float*)d_in[7];  const float* bv = (const float*)d_in[8];
  const float* Wo = (const float*)d_in[9];  const float* bo = (const float*)d_in[10];
  float* out = (float*)d_out;

  char* base = (char*)d_ws;
  #define MB(x) ((size_t)(x) << 20)

  short* Qa   = (short*)(base + MB(0));    // queries split a (dead after mega)
  short* Qb2  = (short*)(base + MB(8));    // queries split b (dead after mega)
  short* Ka   = (short*)(base + MB(16));
  short* Kb2  = (short*)(base + MB(24));
  short* Kc   = (short*)(base + MB(32));   // -> Kbf after mega (combine_k writes)
  short* Vbf  = (short*)(base + MB(40));   // -> CselA/CselB after mega
  float* Qb   = (float*)(base + MB(48));   // Q proj f32 -> P1o after fattn
  short* Vt   = (short*)(base + MB(64));   // written during mega (mode-2 epilogue)
  short* Wqa  = (short*)(base + MB(72));
  short* Wqb  = (short*)(base + MB(74));
  short* Wka  = (short*)(base + MB(76));
  short* Wkb  = (short*)(base + MB(78));
  short* Wkc  = (short*)(base + MB(80));
  short* Wvbf = (short*)(base + MB(82));
  short* Woa  = (short*)(base + MB(84));
  short* Wob  = (short*)(base + MB(86));
  char* sm = base + MB(88);
  double* kpart  = (double*)sm;  sm += 524288;    // [32][32][64] f64
  float*  wt     = (float*)sm;   sm += 131072;    // [32][1024] f32
  double* s0     = (double*)sm;  sm += 512;
  float*  msb    = (float*)sm;   sm += 262144;
  int*    sel    = (int*)sm;     sm += 65536;
  int*    invsel = (int*)sm;     sm += 262144;
  float* Kp1 = (float*)(base + MB(90));    // 16 MiB K split-K partial 1

  // time-multiplexed aliases
  float* Kp0   = out;                       // K split-K partial 0 (out is dead until osel)
  short* Kbf   = Kc;                        // written by combine_k after mega
  short* CselA = Vbf;                       // 1.625 MiB
  short* CselB = (short*)(base + MB(42));   // 1.625 MiB
  float* P1o   = Qb;                        // after fattn

  // ---- 1: all splits in one launch (inputs + weights)
  {
    SplitArgs a;
    a.d[0] = {queries, Qa, Qb2, nullptr, 2, 2048};
    a.d[1] = {keys,    Ka, Kb2, Kc,      3, 2048};
    a.d[2] = {values,  Vbf, nullptr, nullptr, 1, 2048};
    a.d[3] = {Wq, Wqa, Wqb, nullptr, 2, 512};
    a.d[4] = {Wk, Wka, Wkb, Wkc,     3, 512};
    a.d[5] = {Wv, Wvbf, nullptr, nullptr, 1, 512};
    a.d[6] = {Wo, Woa, Wob, nullptr, 2, 512};
    msplit_k<<<dim3(2048,1,7), 256, 0, stream>>>(a);
  }
  // ---- 2: balanced mega GEMM, full tiles: Q(48) + K0(0..48->Kp0) +
  //         K1(48..96->Kp1) + V(16, fused transpose epilogue); 1024 blocks
  {
    GemmArgs g;
    g.d[0] = {{Qa,Qb2,Qa},   {Wqa,Wqb,Wqa},    bq, Qb,  nullptr, 0, 48, 0};
    g.d[1] = {{Ka,Kb2,Kc},   {Wka,Wkb,Wkc},    nullptr, Kp0, nullptr, 0, 48, 1};
    g.d[2] = {{Ka,Kb2,Kc},   {Wka,Wkb,Wkc},    nullptr, Kp1, nullptr, 48, 96, 1};
    g.d[3] = {{Vbf,Vbf,Vbf}, {Wvbf,Wvbf,Wvbf}, bv, nullptr, Vt, 0, 16, 2};
    gemm_mega_k<<<1024, 256, 0, stream>>>(g);
  }
  // ---- 3-6: K combine + ranking chain
  combine_k<<<NBH*32, 256, 0, stream>>>(Kp0, Kp1, bk, Kbf, kpart);
  wtilde_k<<<dim3(NBH,4), 256, 0, stream>>>(Wq, bq, kpart, wt, s0);
  dotqms_k<<<NROWS, 256, 0, stream>>>(queries, Qb, wt, s0, msb);
  select_rank_k<<<NBH*8, 256, 0, stream>>>(msb, sel, invsel);

  // ---- 7: fused attention (inline Q gather; split bf16 Csel; pad rows zeroed)
  fattn_k<<<MTOT/32, 512, 0, stream>>>(Qb, sel, Kbf, Vt, CselA, CselB);

  // ---- 8: output projection (X gathered from Csel via invsel), split-K 2-way
  {
    OselArgs oa = {CselA, CselB, Woa, Wob, out, P1o, invsel};
    gemm_osel_k<<<512, 256, 0, stream>>>(oa);
  }
  // ---- 9: combine + bias
  oadd_k<<<4096, 256, 0, stream>>>(out, P1o, bo);
}

// Round 12
// 279.339 us; speedup vs baseline: 1.9757x; 1.0002x over previous
//
#include <hip/hip_runtime.h>
#include <math.h>

// Problem constants (fixed by setup_inputs)
#define NB 2
#define NL 2048
#define NH 16
#define ND 64
#define NDM 1024
#define NU 409                  // max(1, 2048 // 5)
#define NUP 416                 // NU padded to multiple of 32; 416 = 26*16 = 13*32
#define NBH (NB*NH)             // 32
#define NROWS (NB*NL)           // 4096
#define NRTOT (NB*NH*NL)        // 65536
#define MTOT (NBH*NUP)          // 13312

typedef short bf16x8 __attribute__((ext_vector_type(8)));
typedef short bf16x4 __attribute__((ext_vector_type(4)));
typedef float f32x4  __attribute__((ext_vector_type(4)));

__device__ __forceinline__ short f2bf(float x) {   // RNE f32 -> bf16
  unsigned u = __float_as_uint(x);
  return (short)((u + 0x7FFFu + ((u >> 16) & 1u)) >> 16);
}
__device__ __forceinline__ float bf2f(short s) {
  return __uint_as_float(((unsigned)(unsigned short)s) << 16);
}

__device__ __forceinline__ void gload16(const short* g, short* l) {
  __builtin_amdgcn_global_load_lds(
      (const __attribute__((address_space(1))) void*)g,
      (__attribute__((address_space(3))) void*)l, 16, 0, 0);
}

// ---------------------------------------------------------------- multi-tensor f32 -> bf16 splits
struct SplitDesc { const float* in; short* a; short* b; short* c; int nc; int nblk; };
struct SplitArgs { SplitDesc d[7]; };

__global__ __launch_bounds__(256) void msplit_k(SplitArgs args) {
  const SplitDesc d = args.d[blockIdx.z];
  if ((int)blockIdx.x >= d.nblk) return;
  const size_t i = (size_t)blockIdx.x * 256 + threadIdx.x;
  const float4 x0 = ((const float4*)d.in)[2*i];
  const float4 x1 = ((const float4*)d.in)[2*i + 1];
  float x[8] = {x0.x,x0.y,x0.z,x0.w, x1.x,x1.y,x1.z,x1.w};
  bf16x8 va, vb, vc;
  #pragma unroll
  for (int j = 0; j < 8; ++j) {
    const short A = f2bf(x[j]);
    const float r1 = x[j] - bf2f(A);
    const short B = f2bf(r1);
    va[j] = A; vb[j] = B;
    vc[j] = f2bf(r1 - bf2f(B));
  }
  *(bf16x8*)(d.a + 8*i) = va;
  if (d.nc >= 2) *(bf16x8*)(d.b + 8*i) = vb;
  if (d.nc == 3) *(bf16x8*)(d.c + 8*i) = vc;
}

// ---------------------------------------------------------------- mega projection GEMM (Q/K0/K1/V), full 128x128 tiles
// BK=64, 4 waves 2x2, wave 64x64 = 4x4 16x16 frags.
// chunk pairs (c=step>>4): c0 (a,a), c1 (a,b), c2 (b,a), c3 (a,c), c4 (c,a), c5 (b,b)
// LDS: linear dest for global_load_lds; SOURCE k-slot pre-swizzled s^=(row&7);
// fragment reads apply the same XOR (rule 21).
// 1024 blocks; fid&7 = XCD, jd&3 = desc -> each CU hosts {Q,K0,K1,V}.
// mode 0: SC-scatter f32 + bias (Q)
// mode 1: SC-scatter f32, no bias (K split-K partials)
// mode 2: fused V epilogue: +bias, LDS transpose, coalesced bf16 Vt (bh,d,l)
struct GemmDesc {
  const short* X[3];
  const short* W[3];
  const float* bias;    // may be null
  float* C;             // modes 0/1
  short* Vt;            // mode 2
  int sbeg, send;       // step range; one step = 64 k-elems; chunk = step>>4
  int mode;
};
struct GemmArgs { GemmDesc d[4]; };

__global__ __launch_bounds__(256, 3) void gemm_mega_k(GemmArgs args) {
  __shared__ short As[128*64];   // 16 KB
  __shared__ short Bs[128*64];   // 16 KB
  const int fid = blockIdx.x;
  const int xcd = fid & 7, jd = fid >> 3;   // jd 0..127
  const int s = jd & 3, jj = jd >> 2;       // desc s; tile jj 0..31
  const int tile = (xcd << 5) + jj;         // 0..255
  const int bx = tile & 7, by = tile >> 3;
  const GemmDesc d = args.d[s];
  const int tid = threadIdx.x;
  const int wv = tid >> 6, L = tid & 63;
  const int lr = L & 15, lg = L >> 4;
  const int n0 = bx << 7, m0 = by << 7;
  const int wm = (wv >> 1) << 6, wn = (wv & 1) << 6;
  const int sr = tid >> 3, ssl = tid & 7;

  f32x4 acc[4][4];
  #pragma unroll
  for (int i = 0; i < 4; ++i)
    #pragma unroll
    for (int j = 0; j < 4; ++j) acc[i][j] = (f32x4){0.f,0.f,0.f,0.f};

  for (int step = d.sbeg; step < d.send; ++step) {
    const int c = step >> 4, kk = (step & 15) << 6;
    const short *Xg, *Wg;
    switch (c) {
      case 0:  Xg = d.X[0]; Wg = d.W[0]; break;
      case 1:  Xg = d.X[0]; Wg = d.W[1]; break;
      case 2:  Xg = d.X[1]; Wg = d.W[0]; break;
      case 3:  Xg = d.X[0]; Wg = d.W[2]; break;
      case 4:  Xg = d.X[2]; Wg = d.W[0]; break;
      default: Xg = d.X[1]; Wg = d.W[1]; break;
    }
    #pragma unroll
    for (int j = 0; j < 4; ++j) {
      const int row = (j << 5) + sr;
      const int slot = (ssl ^ (row & 7)) << 3;   // pre-swizzled k-slot
      gload16(Xg + (size_t)(m0 + row) * NDM + kk + slot, As + (j << 11) + (tid << 3));
      gload16(Wg + (size_t)(n0 + row) * NDM + kk + slot, Bs + (j << 11) + (tid << 3));
    }
    __syncthreads();
    #pragma unroll
    for (int c2 = 0; c2 < 2; ++c2) {
      const int sl = (((c2 << 2) + lg) ^ (lr & 7)) << 3;
      bf16x8 af[4], bfr[4];
      #pragma unroll
      for (int t = 0; t < 4; ++t) {
        af[t]  = *(const bf16x8*)(As + ((wm + (t << 4) + lr) << 6) + sl);
        bfr[t] = *(const bf16x8*)(Bs + ((wn + (t << 4) + lr) << 6) + sl);
      }
      #pragma unroll
      for (int mt = 0; mt < 4; ++mt)
        #pragma unroll
        for (int nt = 0; nt < 4; ++nt)
          acc[mt][nt] = __builtin_amdgcn_mfma_f32_16x16x32_bf16(bfr[nt], af[mt], acc[mt][nt], 0, 0, 0);
    }
    __syncthreads();
  }

  if (d.mode == 2) {
    // ---- fused V epilogue: +bias -> bf16 into LDS T(n,m) (XOR col swizzle),
    //      then coalesced 128B-contiguous stores into Vt[bh][d][l].
    #pragma unroll
    for (int nt = 0; nt < 4; ++nt) {
      const int nl = wn + (nt << 4) + (lg << 2);
      const float4 b4 = *(const float4*)(d.bias + n0 + nl);
      #pragma unroll
      for (int j2 = 0; j2 < 4; ++j2) {
        const int row = nl + j2;
        short* Tp = (row & 64) ? Bs : As;
        const int rr = row & 63;
        const float bj = (j2 == 0) ? b4.x : (j2 == 1) ? b4.y : (j2 == 2) ? b4.z : b4.w;
        const int sw = (row & 7) << 3;
        #pragma unroll
        for (int mt = 0; mt < 4; ++mt) {
          const int m = wm + (mt << 4) + lr;
          Tp[rr * 128 + (m ^ sw)] = f2bf(acc[mt][nt][j2] + bj);
        }
      }
    }
    __syncthreads();
    {
      const int r = tid >> 1, seg = tid & 1;
      const short* Tp = (r & 64) ? Bs : As;
      const int rr = r & 63, sw = (r & 7) << 3;
      const int ngl = n0 + r, h = ngl >> 6, dd2 = ngl & 63;
      const int bb = m0 >> 11, ll = m0 & (NL - 1);
      short* dst = d.Vt + (((size_t)((((bb << 4) + h) << 6) + dd2)) << 11) + ll + (seg << 6);
      #pragma unroll
      for (int i = 0; i < 8; ++i)
        *(bf16x8*)(dst + (i << 3)) =
            *(const bf16x8*)(Tp + rr * 128 + (((seg << 6) + (i << 3)) ^ sw));
    }
  } else {
    #pragma unroll
    for (int nt = 0; nt < 4; ++nt) {
      const int n = n0 + wn + (nt << 4) + (lg << 2);
      float4 b4 = make_float4(0.f, 0.f, 0.f, 0.f);
      if (d.bias) b4 = *(const float4*)(d.bias + n);
      #pragma unroll
      for (int mt = 0; mt < 4; ++mt) {
        f32x4 a = acc[mt][nt];
        a[0] += b4.x; a[1] += b4.y; a[2] += b4.z; a[3] += b4.w;
        const int m = m0 + wm + (mt << 4) + lr;
        const int bb = m >> 11, ll = m & (NL - 1);
        const int hh = n >> 6, dd = n & 63;
        *(f32x4*)(d.C + (((size_t)(bb*NH + hh)*NL + ll) << 6) + dd) = a;
      }
    }
  }
}

// ---------------------------------------------------------------- K combine: Kp0+Kp1+bias -> Kbf bf16, khat partials
__global__ __launch_bounds__(256) void combine_k(const float* __restrict__ Kp0,
                                                 const float* __restrict__ Kp1,
                                                 const float* __restrict__ bk,
                                                 short* __restrict__ Kbf,
                                                 double* __restrict__ kpart) {
  __shared__ double sm[4][64];
  const int bh = blockIdx.x >> 5, seg = blockIdx.x & 31;
  const int g = threadIdx.x >> 6, d = threadIdx.x & 63;
  const int h = bh & 15;
  const float bias = bk[(h << 6) + d];
  double acc = 0.0;
  #pragma unroll 4
  for (int i = 0; i < 16; ++i) {
    const int l = (seg << 6) + (i << 2) + g;
    const size_t o = (((size_t)bh * NL + l) << 6) + d;
    const float k = Kp0[o] + Kp1[o] + bias;
    float ss = k * k;
    #pragma unroll
    for (int off = 32; off > 0; off >>= 1) ss += __shfl_xor(ss, off);
    const double inv = 1.0 / sqrt((double)ss);
    Kbf[o] = f2bf(k);
    acc += (double)k * inv;
  }
  sm[g][d] = acc;
  __syncthreads();
  if (threadIdx.x < 64)
    kpart[((((size_t)bh << 5) + seg) << 6) + threadIdx.x] =
        sm[0][threadIdx.x] + sm[1][threadIdx.x] + sm[2][threadIdx.x] + sm[3][threadIdx.x];
}

// ---------------------------------------------------------------- wtilde (+inline kbar reduce): wt[bh][j] f32, s0[bh] f64
__global__ __launch_bounds__(256) void wtilde_k(const float* __restrict__ Wq,
                                                const float* __restrict__ bq,
                                                const double* __restrict__ kpart,
                                                float* __restrict__ wt,
                                                double* __restrict__ s0) {
  __shared__ double kb[64];
  const int bh = blockIdx.x, h = bh & 15;
  const int tid = threadIdx.x;
  if (tid < 64) {
    double s = 0.0;
    #pragma unroll
    for (int seg = 0; seg < 32; ++seg)
      s += kpart[((((size_t)bh << 5) + seg) << 6) + tid];
    kb[tid] = s * (1.0 / NL);
  }
  __syncthreads();
  const int j = (blockIdx.y << 8) + tid;
  double a = 0.0;
  #pragma unroll 8
  for (int d = 0; d < 64; ++d)
    a += (double)Wq[(((size_t)((h << 6) + d)) << 10) + j] * kb[d];
  wt[((size_t)bh << 10) + j] = (float)a;
  if (blockIdx.y == 0 && tid < 64) {
    double p = (double)bq[(h << 6) + tid] * kb[tid];
    #pragma unroll
    for (int off = 32; off > 0; off >>= 1) p += __shfl_xor(p, off);
    if (tid == 0) s0[bh] = p;
  }
}

// ---------------------------------------------------------------- fused dotq+msq: ms[bh][l] = (x.wt + s0)/|q|
__global__ __launch_bounds__(256) void dotqms_k(const float* __restrict__ x,
                                                const float* __restrict__ Qb,
                                                const float* __restrict__ wt,
                                                const double* __restrict__ s0,
                                                float* __restrict__ ms) {
  __shared__ float xs[1024];
  __shared__ double sm[16][16];
  __shared__ double sq[16][16];
  const int r = blockIdx.x, b = r >> 11, l = r & (NL - 1);
  const int tid = threadIdx.x;
  ((float4*)xs)[tid] = ((const float4*)(x + ((size_t)r << 10)))[tid];
  __syncthreads();
  const int h = tid >> 4, t = tid & 15;
  const float* w = wt + ((size_t)((b << 4) + h) << 10);
  double a = 0.0;
  #pragma unroll 8
  for (int i = 0; i < 64; ++i) {
    const int j = t + (i << 4);
    a += (double)xs[j] * (double)w[j];
  }
  sm[h][t] = a;
  const float4 qv = *(const float4*)(Qb + (((size_t)((b << 4) + h) * NL + l) << 6) + (t << 2));
  sq[h][t] = (double)qv.x*qv.x + (double)qv.y*qv.y + (double)qv.z*qv.z + (double)qv.w*qv.w;
  __syncthreads();
  if (tid < 16) {
    double s = 0.0, ssq = 0.0;
    #pragma unroll
    for (int t2 = 0; t2 < 16; ++t2) { s += sm[tid][t2]; ssq += sq[tid][t2]; }
    ms[(((size_t)(b << 4) + tid) << 11) + l] = (float)((s + s0[(b << 4) + tid]) / sqrt(ssq));
  }
}

// ---------------------------------------------------------------- rank-based top-NU selection (+ inverse map; pad -> NU)
__global__ __launch_bounds__(256) void select_rank_k(const float* __restrict__ ms,
                                                     int* __restrict__ sel,
                                                     int* __restrict__ invsel) {
  __shared__ unsigned long long keys[NL];
  const int bh = blockIdx.x >> 3, seg = blockIdx.x & 7;
  const int tid = threadIdx.x;
  for (int l = tid; l < NL; l += 256) {
    unsigned u = __float_as_uint(ms[(size_t)bh * NL + l]);
    u = (u & 0x80000000u) ? ~u : (u | 0x80000000u);   // order-preserving map
    keys[l] = ((unsigned long long)u << 32) | (unsigned)(NL - 1 - l);
  }
  __syncthreads();
  const int r = (seg << 8) + tid;
  const unsigned long long mine = keys[r];
  int cnt = 0;
  #pragma unroll 8
  for (int l = 0; l < NL; ++l) cnt += (keys[l] > mine) ? 1 : 0;
  if (cnt < NU) sel[bh*NU + cnt] = r;
  invsel[(size_t)bh * NL + r] = (cnt < NU) ? cnt : NU;  // NU = zeroed pad row
}

// ---------------------------------------------------------------- fused attention with inline Q gather; split bf16 Csel out
__global__ __launch_bounds__(512) void fattn_k(const float* __restrict__ Qb,
                                               const int* __restrict__ sel,
                                               const short* __restrict__ Kbf,
                                               const short* __restrict__ Vt,
                                               short* __restrict__ Ca,
                                               short* __restrict__ Cb) {
  __shared__ short S[32*2048];        // 128 KB, row stride 4096 B
  __shared__ float inv_s[32];
  int bid = blockIdx.x;
  bid = (bid & 7) * 52 + (bid >> 3);  // 416 = 8*52 XCD chunks
  const int m0 = bid << 5;
  const int bh = m0 / NUP;
  const int u0 = m0 - bh * NUP;
  const int tid = threadIdx.x;
  const int w = tid >> 6, L = tid & 63;
  const int lr = L & 15, lg = L >> 4;

  // ---- Q fragments gathered from f32 Qb via sel (pad rows read row 0, discarded)
  bf16x8 qf[2][2];
  #pragma unroll
  for (int mt = 0; mt < 2; ++mt) {
    const int u = u0 + mt*16 + lr;
    const int lq = (u < NU) ? sel[bh*NU + u] : 0;
    const float* qp = Qb + (((size_t)bh*NL + lq) << 6) + lg*8;
    const float4 q0 = *(const float4*)qp;
    const float4 q1 = *(const float4*)(qp + 4);
    const float4 q2 = *(const float4*)(qp + 32);
    const float4 q3 = *(const float4*)(qp + 36);
    qf[mt][0][0]=f2bf(q0.x); qf[mt][0][1]=f2bf(q0.y); qf[mt][0][2]=f2bf(q0.z); qf[mt][0][3]=f2bf(q0.w);
    qf[mt][0][4]=f2bf(q1.x); qf[mt][0][5]=f2bf(q1.y); qf[mt][0][6]=f2bf(q1.z); qf[mt][0][7]=f2bf(q1.w);
    qf[mt][1][0]=f2bf(q2.x); qf[mt][1][1]=f2bf(q2.y); qf[mt][1][2]=f2bf(q2.z); qf[mt][1][3]=f2bf(q2.w);
    qf[mt][1][4]=f2bf(q3.x); qf[mt][1][5]=f2bf(q3.y); qf[mt][1][6]=f2bf(q3.z); qf[mt][1][7]=f2bf(q3.w);
  }
  const int nb = w << 8;
  const short* kb0 = Kbf + (((size_t)bh*NL + nb + lr) << 6) + lg*8;
  #pragma unroll 2
  for (int nt = 0; nt < 16; ++nt) {
    const short* kp = kb0 + ((size_t)nt << 10);
    const bf16x8 kf0 = *(const bf16x8*)kp;
    const bf16x8 kf1 = *(const bf16x8*)(kp + 32);
    #pragma unroll
    for (int mt = 0; mt < 2; ++mt) {
      f32x4 a = {0.f,0.f,0.f,0.f};
      a = __builtin_amdgcn_mfma_f32_16x16x32_bf16(kf0, qf[mt][0], a, 0, 0, 0);
      a = __builtin_amdgcn_mfma_f32_16x16x32_bf16(kf1, qf[mt][1], a, 0, 0, 0);
      const int m = mt*16 + lr;
      bf16x4 o;
      #pragma unroll
      for (int r = 0; r < 4; ++r) o[r] = f2bf(a[r] * 0.125f);
      const int byteoff = (m << 12) + ((((nb + nt*16 + lg*4) << 1)) ^ ((m & 7) << 4));
      *(bf16x4*)((char*)S + byteoff) = o;
    }
  }
  __syncthreads();

  #pragma unroll
  for (int j = 0; j < 4; ++j) {
    const int R = (w << 2) + j;
    char* rowp = (char*)S + (R << 12);
    const int sw = (R & 7) << 4;
    bf16x8 v[4];
    #pragma unroll
    for (int i = 0; i < 4; ++i)
      v[i] = *(const bf16x8*)(rowp + (((L << 6) + (i << 4)) ^ sw));
    float f[32];
    #pragma unroll
    for (int i = 0; i < 4; ++i)
      #pragma unroll
      for (int e = 0; e < 8; ++e) f[i*8+e] = bf2f(v[i][e]);
    float mx = f[0];
    #pragma unroll
    for (int i = 1; i < 32; ++i) mx = fmaxf(mx, f[i]);
    #pragma unroll
    for (int off = 32; off > 0; off >>= 1) mx = fmaxf(mx, __shfl_xor(mx, off));
    float sum = 0.f;
    #pragma unroll
    for (int i = 0; i < 32; ++i) { f[i] = __expf(f[i] - mx); sum += f[i]; }
    #pragma unroll
    for (int off = 32; off > 0; off >>= 1) sum += __shfl_xor(sum, off);
    bf16x8 p[4];
    #pragma unroll
    for (int i = 0; i < 4; ++i)
      #pragma unroll
      for (int e = 0; e < 8; ++e) p[i][e] = f2bf(f[i*8+e]);
    #pragma unroll
    for (int i = 0; i < 4; ++i)
      *(bf16x8*)(rowp + (((L << 6) + (i << 4)) ^ sw)) = p[i];
    if (L == 0) inv_s[R] = 1.f / sum;
  }
  __syncthreads();

  {
    const int mt = w & 1, dt = w >> 1;
    const int m = mt*16 + lr;
    const char* arow = (const char*)S + (m << 12);
    const int sw = (m & 7) << 4;
    const short* vrow = Vt + (((size_t)bh*ND + dt*16 + lr) << 11) + lg*8;
    f32x4 acc0 = {0.f,0.f,0.f,0.f}, acc1 = {0.f,0.f,0.f,0.f};
    for (int k0 = 0; k0 < NL; k0 += 64) {
      const bf16x8 p0 = *(const bf16x8*)(arow + ((((k0 + lg*8) << 1)) ^ sw));
      const bf16x8 p1 = *(const bf16x8*)(arow + ((((k0 + 32 + lg*8) << 1)) ^ sw));
      const bf16x8 v0 = *(const bf16x8*)(vrow + k0);
      const bf16x8 v1 = *(const bf16x8*)(vrow + k0 + 32);
      acc0 = __builtin_amdgcn_mfma_f32_16x16x32_bf16(p0, v0, acc0, 0, 0, 0);
      acc1 = __builtin_amdgcn_mfma_f32_16x16x32_bf16(p1, v1, acc1, 0, 0, 0);
    }
    const int ub = u0 + mt*16 + (lg << 2);
    #pragma unroll
    for (int r = 0; r < 4; ++r) {
      float val = (acc0[r] + acc1[r]) * inv_s[mt*16 + (lg << 2) + r];
      if (ub + r >= NU) val = 0.f;                 // zero pad rows (incl. row NU)
      const size_t off = (((size_t)m0 + mt*16 + (lg << 2) + r) << 6) + dt*16 + lr;
      const short A = f2bf(val);
      Ca[off] = A;
      Cb[off] = f2bf(val - bf2f(A));
    }
  }
}

// ---------------------------------------------------------------- O projection GEMM (X gathered from Csel via invsel)
// 768 blocks; split-K 3-way interleaved per CU (3 blocks/CU). Full tile.
struct OselArgs {
  const short* Xa; const short* Xb;
  const short* Wa; const short* Wb;
  float* C0; float* C1; float* C2;   // thirds: steps [0,16) [16,32) [32,48)
  const int* invsel;
};

__global__ __launch_bounds__(256, 3) void gemm_osel_k(OselArgs ar) {
  __shared__ short As[128*64];   // 16 KB
  __shared__ short Bs[128*64];   // 16 KB
  __shared__ int utbl[2048];     // 8 KB
  const int fid = blockIdx.x;
  const int xcd = fid & 7, jd = fid >> 3;   // jd 0..95
  const int zi = jd % 3;
  const int o = (xcd << 5) + (jd / 3);      // 0..255
  const int bx = o & 7, by = o >> 3;
  const int sbeg = zi << 4, send = sbeg + 16;
  float* C = (zi == 0) ? ar.C0 : (zi == 1) ? ar.C1 : ar.C2;
  const int tid = threadIdx.x;
  const int wv = tid >> 6, L = tid & 63;
  const int lr = L & 15, lg = L >> 4;
  const int n0 = bx << 7, m0 = by << 7;
  const int wm = (wv >> 1) << 6, wn = (wv & 1) << 6;
  const int sr = tid >> 3, ssl = tid & 7;
  const int b2 = by >> 4;

  #pragma unroll
  for (int e = 0; e < 8; ++e) {
    const int idx = (tid << 3) + e;             // 0..2047
    const int row = idx >> 4, h = idx & 15;
    utbl[idx] = ar.invsel[((((size_t)b2 << 4) + h) << 11) + ((m0 + row) & (NL - 1))];
  }
  __syncthreads();

  f32x4 acc[4][4];
  #pragma unroll
  for (int i = 0; i < 4; ++i)
    #pragma unroll
    for (int j = 0; j < 4; ++j) acc[i][j] = (f32x4){0.f,0.f,0.f,0.f};

  for (int step = sbeg; step < send; ++step) {
    const int c = step >> 4, kk = (step & 15) << 6;
    const short* Wg = (c == 1) ? ar.Wb : ar.Wa;   // c0:(a,a) c1:(a,b) c2:(b,a)
    const short* Xs = (c == 2) ? ar.Xb : ar.Xa;
    #pragma unroll
    for (int j = 0; j < 4; ++j) {
      const int row = (j << 5) + sr;
      const int slot = (ssl ^ (row & 7)) << 3;
      const int h = step & 15;                  // one head per 64-wide step
      const int u = utbl[(row << 4) + h];
      gload16(Xs + (((size_t)((b2 << 4) + h) * NUP + u) << 6) + slot,
              As + (j << 11) + (tid << 3));
      gload16(Wg + (size_t)(n0 + row) * NDM + kk + slot, Bs + (j << 11) + (tid << 3));
    }
    __syncthreads();
    #pragma unroll
    for (int c2 = 0; c2 < 2; ++c2) {
      const int sl = (((c2 << 2) + lg) ^ (lr & 7)) << 3;
      bf16x8 af[4], bfr[4];
      #pragma unroll
      for (int t = 0; t < 4; ++t) {
        af[t]  = *(const bf16x8*)(As + ((wm + (t << 4) + lr) << 6) + sl);
        bfr[t] = *(const bf16x8*)(Bs + ((wn + (t << 4) + lr) << 6) + sl);
      }
      #pragma unroll
      for (int mt = 0; mt < 4; ++mt)
        #pragma unroll
        for (int nt = 0; nt < 4; ++nt)
          acc[mt][nt] = __builtin_amdgcn_mfma_f32_16x16x32_bf16(bfr[nt], af[mt], acc[mt][nt], 0, 0, 0);
    }
    __syncthreads();
  }

  #pragma unroll
  for (int nt = 0; nt < 4; ++nt) {
    const int n = n0 + wn + (nt << 4) + (lg << 2);
    #pragma unroll
    for (int mt = 0; mt < 4; ++mt) {
      const int m = m0 + wm + (mt << 4) + lr;
      *(f32x4*)(C + ((size_t)m << 10) + n) = acc[mt][nt];
    }
  }
}

// ---------------------------------------------------------------- out += P1 + P2 + bias
__global__ __launch_bounds__(256) void oadd_k(float* __restrict__ out,
                                              const float* __restrict__ P1,
                                              const float* __restrict__ P2,
                                              const float* __restrict__ bo) {
  const size_t i4 = (size_t)blockIdx.x * 256 + threadIdx.x;
  const size_t i = i4 << 2;
  float4 a = *(float4*)(out + i);
  const float4 b = *(const float4*)(P1 + i);
  const float4 c = *(const float4*)(P2 + i);
  const float4 d = *(const float4*)(bo + ((i4 & 255) << 2));
  a.x += b.x + c.x + d.x; a.y += b.y + c.y + d.y;
  a.z += b.z + c.z + d.z; a.w += b.w + c.w + d.w;
  *(float4*)(out + i) = a;
}

// ---------------------------------------------------------------- launch
extern "C" void kernel_launch(void* const* d_in, const int* in_sizes, int n_in,
                              void* d_out, int out_size, void* d_ws, size_t ws_size,
                              hipStream_t stream)
{
  (void)in_sizes; (void)n_in; (void)out_size; (void)ws_size;
  const float* queries = (const float*)d_in[0];
  const float* keys    = (const float*)d_in[1];
  const float* values  = (const float*)d_in[2];
  const float* Wq = (const float*)d_in[3];  const float* bq = (const float*)d_in[4];
  const float* Wk = (const float*)d_in[5];  const float* bk = (const float*)d_in[6];
  const float* Wv = (const float*)d_in[7];  const float* bv = (const float*)d_in[8];
  const float* Wo = (const float*)d_in[9];  const float* bo = (const float*)d_in[10];
  float* out = (float*)d_out;

  char* base = (char*)d_ws;
  #define MB(x) ((size_t)(x) << 20)

  short* Qa   = (short*)(base + MB(0));    // queries split a (dead after mega)
  short* Qb2  = (short*)(base + MB(8));    // queries split b (dead after mega)
  short* Ka   = (short*)(base + MB(16));   // -> P2 (osel partial) after mega
  short* Kb2  = (short*)(base + MB(24));
  short* Kc   = (short*)(base + MB(32));   // -> Kbf after mega (combine_k writes)
  short* Vbf  = (short*)(base + MB(40));   // -> CselA/CselB after mega
  float* Qb   = (float*)(base + MB(48));   // Q proj f32 -> P1o after fattn
  short* Vt   = (short*)(base + MB(64));   // written during mega (mode-2 epilogue)
  short* Wqa  = (short*)(base + MB(72));
  short* Wqb  = (short*)(base + MB(74));
  short* Wka  = (short*)(base + MB(76));
  short* Wkb  = (short*)(base + MB(78));
  short* Wkc  = (short*)(base + MB(80));
  short* Wvbf = (short*)(base + MB(82));
  short* Woa  = (short*)(base + MB(84));
  short* Wob  = (short*)(base + MB(86));
  char* sm = base + MB(88);
  double* kpart  = (double*)sm;  sm += 524288;    // [32][32][64] f64
  float*  wt     = (float*)sm;   sm += 131072;    // [32][1024] f32
  double* s0     = (double*)sm;  sm += 512;
  float*  msb    = (float*)sm;   sm += 262144;
  int*    sel    = (int*)sm;     sm += 65536;
  int*    invsel = (int*)sm;     sm += 262144;
  float* Kp1 = (float*)(base + MB(90));    // 16 MiB K split-K partial 1

  // time-multiplexed aliases
  float* Kp0   = out;                       // K split-K partial 0 (out dead until osel)
  short* Kbf   = Kc;                        // written by combine_k after mega
  short* CselA = Vbf;                       // 1.625 MiB
  short* CselB = (short*)(base + MB(42));   // 1.625 MiB
  float* P1o   = Qb;                        // after fattn
  float* P2o   = (float*)Ka;                // 16 MiB (Ka+Kb2 region, dead after mega)

  // ---- 1: all splits in one launch (inputs + weights)
  {
    SplitArgs a;
    a.d[0] = {queries, Qa, Qb2, nullptr, 2, 2048};
    a.d[1] = {keys,    Ka, Kb2, Kc,      3, 2048};
    a.d[2] = {values,  Vbf, nullptr, nullptr, 1, 2048};
    a.d[3] = {Wq, Wqa, Wqb, nullptr, 2, 512};
    a.d[4] = {Wk, Wka, Wkb, Wkc,     3, 512};
    a.d[5] = {Wv, Wvbf, nullptr, nullptr, 1, 512};
    a.d[6] = {Wo, Woa, Wob, nullptr, 2, 512};
    msplit_k<<<dim3(2048,1,7), 256, 0, stream>>>(a);
  }
  // ---- 2: balanced mega GEMM, full tiles: Q(48) + K0(0..48->Kp0) +
  //         K1(48..96->Kp1) + V(16, fused LDS-transpose epilogue); 1024 blocks
  {
    GemmArgs g;
    g.d[0] = {{Qa,Qb2,Qa},   {Wqa,Wqb,Wqa},    bq, Qb,  nullptr, 0, 48, 0};
    g.d[1] = {{Ka,Kb2,Kc},   {Wka,Wkb,Wkc},    nullptr, Kp0, nullptr, 0, 48, 1};
    g.d[2] = {{Ka,Kb2,Kc},   {Wka,Wkb,Wkc},    nullptr, Kp1, nullptr, 48, 96, 1};
    g.d[3] = {{Vbf,Vbf,Vbf}, {Wvbf,Wvbf,Wvbf}, bv, nullptr, Vt, 0, 16, 2};
    gemm_mega_k<<<1024, 256, 0, stream>>>(g);
  }
  // ---- 3-6: K combine + ranking chain
  combine_k<<<NBH*32, 256, 0, stream>>>(Kp0, Kp1, bk, Kbf, kpart);
  wtilde_k<<<dim3(NBH,4), 256, 0, stream>>>(Wq, bq, kpart, wt, s0);
  dotqms_k<<<NROWS, 256, 0, stream>>>(queries, Qb, wt, s0, msb);
  select_rank_k<<<NBH*8, 256, 0, stream>>>(msb, sel, invsel);

  // ---- 7: fused attention (inline Q gather; split bf16 Csel; pad rows zeroed)
  fattn_k<<<MTOT/32, 512, 0, stream>>>(Qb, sel, Kbf, Vt, CselA, CselB);

  // ---- 8: output projection (X gathered from Csel via invsel), split-K 3-way
  {
    OselArgs oa = {CselA, CselB, Woa, Wob, out, P1o, P2o, invsel};
    gemm_osel_k<<<768, 256, 0, stream>>>(oa);
  }
  // ---- 9: combine + bias
  oadd_k<<<4096, 256, 0, stream>>>(out, P1o, P2o, bo);
}